// Round 11
// baseline (783.866 us; speedup 1.0000x reference)
//
#include <hip/hip_runtime.h>
#include <math.h>

#define NROWS 16384
#define GATES 5
#define HDIM 512
#define KPAD 416   // stage-1 K: 400 real cols padded to 13*32

using bf16x8 = __attribute__((ext_vector_type(8))) short;
using f32x4  = __attribute__((ext_vector_type(4))) float;

__device__ inline float b2f(unsigned short s) {
  unsigned int u = ((unsigned int)s) << 16;
  return __builtin_bit_cast(float, u);
}
__device__ inline unsigned short f2b(float f) {
  unsigned int u = __builtin_bit_cast(unsigned int, f);
  u += 0x7fffu + ((u >> 16) & 1u);   // RNE
  return (unsigned short)(u >> 16);
}

__device__ inline float fast_sigmoid(float x) {
  float t = __builtin_amdgcn_exp2f(-1.4426950408889634f * x);
  return __builtin_amdgcn_rcpf(1.0f + t);
}
__device__ inline float fast_tanh(float x) {
  float t = __builtin_amdgcn_exp2f(2.8853900817779268f * x);
  return 1.0f - 2.0f * __builtin_amdgcn_rcpf(1.0f + t);
}

__device__ inline void gload_lds16(const unsigned short* g, unsigned short* l) {
  __builtin_amdgcn_global_load_lds(
      (const __attribute__((address_space(1))) unsigned int*)(g),
      (__attribute__((address_space(3))) unsigned int*)(l), 16, 0, 0);
}

// ---------------- packing / conversion kernels (f32 -> bf16) ----------------

__global__ void pack_x(const float* __restrict__ word,
                       const float* __restrict__ tag,
                       const float* __restrict__ rel,
                       unsigned short* __restrict__ xcat) {
  int idx = blockIdx.x * 256 + threadIdx.x;       // N*KPAD
  if (idx >= NROWS * KPAD) return;
  int n = idx / KPAD, c = idx % KPAD;
  float v = 0.f;
  if (c < 300)      v = word[n * 300 + c];
  else if (c < 350) v = tag[n * 50 + (c - 300)];
  else if (c < 400) v = rel[n * 50 + (c - 350)];
  xcat[idx] = f2b(v);
}

__global__ void pack_w(const float* __restrict__ Ww,
                       const float* __restrict__ Wt,
                       const float* __restrict__ Wr,
                       unsigned short* __restrict__ Wcat) {
  int idx = blockIdx.x * 256 + threadIdx.x;       // 2560*KPAD
  if (idx >= GATES * HDIM * KPAD) return;
  int gh = idx / KPAD;
  int c = idx % KPAD;
  float v = 0.f;
  if (c < 300)      v = Ww[gh * 300 + c];
  else if (c < 350) v = Wt[gh * 50 + (c - 300)];
  else if (c < 400) v = Wr[gh * 50 + (c - 350)];
  Wcat[idx] = f2b(v);
}

__global__ void cvt_w4(const float* __restrict__ a, const float* __restrict__ b,
                       const float* __restrict__ c, const float* __restrict__ d,
                       unsigned short* oa, unsigned short* ob,
                       unsigned short* oc, unsigned short* od) {
  const float* in; unsigned short* out;
  switch (blockIdx.y) {
    case 0: in = a; out = oa; break;
    case 1: in = b; out = ob; break;
    case 2: in = c; out = oc; break;
    default: in = d; out = od; break;
  }
  int i = (blockIdx.x * 256 + threadIdx.x) * 4;   // 1310720 elems
  float4 v = *(const float4*)(in + i);
  ushort4 o;
  o.x = f2b(v.x); o.y = f2b(v.y); o.z = f2b(v.z); o.w = f2b(v.w);
  *(ushort4*)(out + i) = o;
}

__global__ void cvt_x2(const float* __restrict__ a, const float* __restrict__ b,
                       unsigned short* oa, unsigned short* ob) {
  const float* in = blockIdx.y ? b : a;
  unsigned short* out = blockIdx.y ? ob : oa;
  int i = (blockIdx.x * 256 + threadIdx.x) * 4;   // 8388608 elems
  float4 v = *(const float4*)(in + i);
  ushort4 o;
  o.x = f2b(v.x); o.y = f2b(v.y); o.z = f2b(v.z); o.w = f2b(v.w);
  *(ushort4*)(out + i) = o;
}

__global__ void pack_bias(const float* __restrict__ bw, const float* __restrict__ bt,
                          const float* __restrict__ br, const float* __restrict__ bh,
                          const float* __restrict__ bl, const float* __restrict__ bhp,
                          const float* __restrict__ bk,
                          float* bias0, float* bias1, float* bias2, float* biasD) {
  int i = blockIdx.x * 256 + threadIdx.x;
  if (i < GATES * HDIM) {
    bias0[i] = bw[i] + bt[i] + br[i];
    bias1[i] = bh[i];
    bias2[i] = bl[i];
    biasD[i] = bhp[i] + bk[i];
  }
}

// ---------------- GEMM: 256x256 tile, BK=32, 8 waves, 2-phase/K-tile ---------
// K-loop identical to round 9 (verified). NEW: coalesced epilogue — acc+bias
// staged to LDS (bf16, stride-260 pad, conflict-free) in 4 passes of 64 rows,
// then linear b128 reads + 16B/lane global stores. Madd (MODE 1) read in the
// same linear pass. Replaces 128 scattered 2B stores/thread (32B-fragment
// granularity — the fixed per-dispatch cost identified in round 10).
// MODE 0: Out = tanh(A*W^T + bias); MODE 1: + A2*W2^T + Madd, gate activation.

template<int MODE>
__global__ __launch_bounds__(512, 2) void gemm_big(
    const unsigned short* __restrict__ A1, const unsigned short* __restrict__ A2,
    const unsigned short* __restrict__ W1, const unsigned short* __restrict__ W2,
    const float* __restrict__ bias,
    const unsigned short* __restrict__ Madd,
    unsigned short* __restrict__ Out,
    int aPerGate, int S, int ld)
{
  __shared__ __align__(16) unsigned short smem[32768];   // 64 KB, aliased
  unsigned short* Ab0 = smem;            // staging A [2][8192]
  unsigned short* Bb0 = smem + 16384;    // staging B [2][8192]
  unsigned short* eps = smem;            // epilogue [64][260]

  const int t = threadIdx.x;
  const int row0  = blockIdx.x * 256;
  const int gcol0 = blockIdx.y * 256;          // [0,2560)
  const int g = gcol0 >> 9;
  const size_t aslab = aPerGate ? (size_t)g * NROWS * ld : 0;

  const int wid = t >> 6, l = t & 63;
  const int wrow = (wid >> 2) * 128;
  const int wcol = (wid & 3) * 64;
  const int fr = l & 15, q = l >> 4;

  f32x4 acc[8][4];
#pragma unroll
  for (int mi = 0; mi < 8; ++mi)
#pragma unroll
    for (int ni = 0; ni < 4; ++ni)
      acc[mi][ni] = (f32x4){0.f, 0.f, 0.f, 0.f};

  auto stage = [&](int c, int buf) {
    const unsigned short* Asrc; const unsigned short* Wsrc; int kloc;
    if (MODE == 1 && c >= 16) { Asrc = A2;         Wsrc = W2; kloc = (c - 16) * 32; }
    else                      { Asrc = A1 + aslab; Wsrc = W1; kloc = c * 32; }
#pragma unroll
    for (int j = 0; j < 2; ++j) {
      const int r  = j * 128 + (t >> 2);
      const int sg = ((t & 3) ^ (r & 3)) * 8;
      gload_lds16(Asrc + (size_t)(row0 + r) * ld + kloc + sg,  &Ab0[buf * 8192 + j * 4096 + t * 8]);
      gload_lds16(Wsrc + (size_t)(gcol0 + r) * ld + kloc + sg, &Bb0[buf * 8192 + j * 4096 + t * 8]);
    }
  };

  stage(0, 0);
  asm volatile("s_waitcnt vmcnt(0)" ::: "memory");
  __builtin_amdgcn_s_barrier();

  bf16x8 bq[4];
  for (int s = 0; s < S; ++s) {
    const int buf = s & 1;
#pragma unroll
    for (int p = 0; p < 2; ++p) {
      bf16x8 af[4];
#pragma unroll
      for (int mi = 0; mi < 4; ++mi) {
        const int r = wrow + (p * 4 + mi) * 16 + fr;
        af[mi] = *reinterpret_cast<const bf16x8*>(&Ab0[buf * 8192 + r * 32 + ((q ^ (r & 3)) * 8)]);
      }
      if (p == 0) {
#pragma unroll
        for (int ni = 0; ni < 4; ++ni) {
          const int r = wcol + ni * 16 + fr;
          bq[ni] = *reinterpret_cast<const bf16x8*>(&Bb0[buf * 8192 + r * 32 + ((q ^ (r & 3)) * 8)]);
        }
        if (s + 1 < S) stage(s + 1, buf ^ 1);
      }
      asm volatile("s_waitcnt lgkmcnt(0)" ::: "memory");
      __builtin_amdgcn_sched_barrier(0);
      __builtin_amdgcn_s_setprio(1);
#pragma unroll
      for (int mi = 0; mi < 4; ++mi)
#pragma unroll
        for (int ni = 0; ni < 4; ++ni)
          acc[p * 4 + mi][ni] = __builtin_amdgcn_mfma_f32_16x16x32_bf16(af[mi], bq[ni], acc[p * 4 + mi][ni], 0, 0, 0);
      __builtin_amdgcn_s_setprio(0);
      if (p == 0) __builtin_amdgcn_s_barrier();
    }
    asm volatile("s_waitcnt vmcnt(0)" ::: "memory");
    __builtin_amdgcn_s_barrier();
  }

  // ---- coalesced epilogue: 4 passes of 64 rows through LDS ----
  const size_t NM = (size_t)NROWS * HDIM;
  unsigned short* outg = Out + (size_t)g * NM;
  const int colbase = gcol0 & 511;
  float bv[4];
#pragma unroll
  for (int ni = 0; ni < 4; ++ni)
    bv[ni] = bias[g * HDIM + colbase + wcol + ni * 16 + fr];

  const int erow = t >> 3;                 // 0..63
  const int ecc  = (t & 7) * 32;           // col chunk (shorts)

  for (int h = 0; h < 4; ++h) {
    __builtin_amdgcn_s_barrier();          // prior read-pass done
    if ((wid >> 2) == (h >> 1)) {          // owning wave-group writes
      const int mib = (h & 1) * 4;
#pragma unroll
      for (int mi2 = 0; mi2 < 4; ++mi2) {
#pragma unroll
        for (int ni = 0; ni < 4; ++ni) {
          const int col = wcol + ni * 16 + fr;
#pragma unroll
          for (int j = 0; j < 4; ++j) {
            const int rl = mi2 * 16 + q * 4 + j;
            eps[rl * 260 + col] = f2b(acc[mib + mi2][ni][j] + bv[ni]);
          }
        }
      }
    }
    __builtin_amdgcn_s_barrier();
    const int gr = row0 + h * 64 + erow;
#pragma unroll
    for (int v = 0; v < 4; ++v) {
      bf16x8 pv = *reinterpret_cast<const bf16x8*>(&eps[erow * 260 + ecc + v * 8]);
      bf16x8 ov;
      if (MODE == 1) {
        bf16x8 mv = *reinterpret_cast<const bf16x8*>(
            Madd + (size_t)g * NM + (size_t)gr * HDIM + colbase + ecc + v * 8);
#pragma unroll
        for (int e = 0; e < 8; ++e) {
          float f = b2f((unsigned short)pv[e]) + b2f((unsigned short)mv[e]);
          f = (g < 4) ? fast_sigmoid(f) : fast_tanh(f);
          ov[e] = (short)f2b(f);
        }
      } else {
#pragma unroll
        for (int e = 0; e < 8; ++e)
          ov[e] = (short)f2b(fast_tanh(b2f((unsigned short)pv[e])));
      }
      *reinterpret_cast<bf16x8*>(&outg[(size_t)gr * HDIM + colbase + ecc + v * 8]) = ov;
    }
  }
}

// ---------------- final elementwise combine (f32 q/c_prev, f32 out) ---------

__device__ inline float exb(const uint4& v, int j) {
  unsigned int wd = ((const unsigned int*)&v)[j >> 1];
  return b2f((unsigned short)(wd >> ((j & 1) * 16)));
}

__global__ void combine(const unsigned short* __restrict__ gates,
                        const float* __restrict__ q,
                        const float* __restrict__ cp,
                        float* __restrict__ out) {
  const size_t NM = (size_t)NROWS * HDIM;
  size_t i8 = ((size_t)blockIdx.x * 256 + threadIdx.x) * 8;
  if (i8 >= NM) return;
  uint4 gi = *(const uint4*)(gates + 0 * NM + i8);
  uint4 gf = *(const uint4*)(gates + 1 * NM + i8);
  uint4 gl = *(const uint4*)(gates + 2 * NM + i8);
  uint4 go = *(const uint4*)(gates + 3 * NM + i8);
  uint4 gu = *(const uint4*)(gates + 4 * NM + i8);
  float4 q0 = *(const float4*)(q + i8);
  float4 q1 = *(const float4*)(q + i8 + 4);
  float4 p0 = *(const float4*)(cp + i8);
  float4 p1 = *(const float4*)(cp + i8 + 4);
  float qv[8] = {q0.x, q0.y, q0.z, q0.w, q1.x, q1.y, q1.z, q1.w};
  float pv[8] = {p0.x, p0.y, p0.z, p0.w, p1.x, p1.y, p1.z, p1.w};
  float hv[8], cv[8];
#pragma unroll
  for (int j = 0; j < 8; ++j) {
    float c = exb(gi, j) * exb(gu, j) + exb(gf, j) * qv[j] + exb(gl, j) * pv[j];
    hv[j] = exb(go, j) * fast_tanh(c);
    cv[j] = c;
  }
  *(float4*)(out + i8)      = make_float4(hv[0], hv[1], hv[2], hv[3]);
  *(float4*)(out + i8 + 4)  = make_float4(hv[4], hv[5], hv[6], hv[7]);
  *(float4*)(out + NM + i8)     = make_float4(cv[0], cv[1], cv[2], cv[3]);
  *(float4*)(out + NM + i8 + 4) = make_float4(cv[4], cv[5], cv[6], cv[7]);
}

// ---------------- launch ----------------

extern "C" void kernel_launch(void* const* d_in, const int* in_sizes, int n_in,
                              void* d_out, int out_size, void* d_ws, size_t ws_size,
                              hipStream_t stream) {
  const float* word  = (const float*)d_in[0];
  const float* tag   = (const float*)d_in[1];
  const float* rel   = (const float*)d_in[2];
  const float* kin   = (const float*)d_in[3];
  const float* qin   = (const float*)d_in[4];
  const float* hprev = (const float*)d_in[5];
  const float* cprev = (const float*)d_in[6];
  const float* Ww    = (const float*)d_in[7];
  const float* bw    = (const float*)d_in[8];
  const float* Wt    = (const float*)d_in[9];
  const float* bt    = (const float*)d_in[10];
  const float* Wr    = (const float*)d_in[11];
  const float* br    = (const float*)d_in[12];
  const float* Wh    = (const float*)d_in[13];
  const float* bh    = (const float*)d_in[14];
  const float* Wl    = (const float*)d_in[15];
  const float* bl    = (const float*)d_in[16];
  const float* Whp   = (const float*)d_in[17];
  const float* bhp   = (const float*)d_in[18];
  const float* Wk    = (const float*)d_in[19];
  const float* bk    = (const float*)d_in[20];

  char* ws = (char*)d_ws;
  unsigned short* xcat   = (unsigned short*)(ws);                 // 13,631,488 B
  unsigned short* Wcat   = (unsigned short*)(ws + 13631488);      //  2,129,920 B
  unsigned short* Whb    = (unsigned short*)(ws + 15761408);      //  2,621,440 B
  unsigned short* Wlb    = (unsigned short*)(ws + 18382848);
  unsigned short* Whpb   = (unsigned short*)(ws + 21004288);
  unsigned short* Wkb    = (unsigned short*)(ws + 23625728);
  unsigned short* hprevb = (unsigned short*)(ws + 26247168);      // 16,777,216 B
  unsigned short* kb16   = (unsigned short*)(ws + 43024384);      // 16,777,216 B
  float* bias0           = (float*)(ws + 59801600);
  float* bias1           = (float*)(ws + 59811840);
  float* bias2           = (float*)(ws + 59822080);
  float* biasD           = (float*)(ws + 59832320);
  unsigned short* bufA   = (unsigned short*)(ws + 59842560);      // 83,886,080 B
  unsigned short* bufB   = (unsigned short*)(ws + 143728640);     // 83,886,080 B
  // total: 227,614,720 B

  pack_x<<<26624, 256, 0, stream>>>(word, tag, rel, xcat);
  pack_w<<<4160, 256, 0, stream>>>(Ww, Wt, Wr, Wcat);
  cvt_w4<<<dim3(1280, 4), 256, 0, stream>>>(Wh, Wl, Whp, Wk, Whb, Wlb, Whpb, Wkb);
  cvt_x2<<<dim3(8192, 2), 256, 0, stream>>>(hprev, kin, hprevb, kb16);
  pack_bias<<<10, 256, 0, stream>>>(bw, bt, br, bh, bl, bhp, bk, bias0, bias1, bias2, biasD);

  dim3 grid(NROWS / 256, (GATES * HDIM) / 256);   // 64 x 10
  // h0 = tanh(xcat W0^T + b0)            K=416 (13 tiles)
  gemm_big<0><<<grid, 512, 0, stream>>>(xcat, nullptr, Wcat, nullptr, bias0, nullptr, bufA, 0, 13, KPAD);
  // h1 = tanh(h0 Whid^T + bhid)          K=512
  gemm_big<0><<<grid, 512, 0, stream>>>(bufA, nullptr, Whb, nullptr, bias1, nullptr, bufB, 1, 16, HDIM);
  // m = tanh(h1 Wlast^T + blast)         K=512
  gemm_big<0><<<grid, 512, 0, stream>>>(bufB, nullptr, Wlb, nullptr, bias2, nullptr, bufA, 1, 16, HDIM);
  // gates = act(hprev Whp^T + k Wk^T + biasD + m)    K=1024
  gemm_big<1><<<grid, 512, 0, stream>>>(hprevb, kb16, Whpb, Wkb, biasD, bufA, bufB, 0, 32, HDIM);
  // c = i*u + f_down*q + f_left*c_prev ; h = o*tanh(c)
  combine<<<4096, 256, 0, stream>>>(bufB, qin, cprev, (float*)d_out);
}

// Round 12
// 485.660 us; speedup vs baseline: 1.6140x; 1.6140x over previous
//
#include <hip/hip_runtime.h>
#include <math.h>

#define NROWS 16384
#define GATES 5
#define HDIM 512
#define KPAD 416   // stage-1 K: 400 real cols padded to 13*32

using bf16x8 = __attribute__((ext_vector_type(8))) short;
using f32x4  = __attribute__((ext_vector_type(4))) float;

__device__ inline float b2f(unsigned short s) {
  unsigned int u = ((unsigned int)s) << 16;
  return __builtin_bit_cast(float, u);
}
__device__ inline unsigned short f2b(float f) {
  unsigned int u = __builtin_bit_cast(unsigned int, f);
  u += 0x7fffu + ((u >> 16) & 1u);   // RNE
  return (unsigned short)(u >> 16);
}

__device__ inline float fast_sigmoid(float x) {
  float t = __builtin_amdgcn_exp2f(-1.4426950408889634f * x);
  return __builtin_amdgcn_rcpf(1.0f + t);
}
__device__ inline float fast_tanh(float x) {
  float t = __builtin_amdgcn_exp2f(2.8853900817779268f * x);
  return 1.0f - 2.0f * __builtin_amdgcn_rcpf(1.0f + t);
}

__device__ inline void gload_lds16(const unsigned short* g, unsigned short* l) {
  __builtin_amdgcn_global_load_lds(
      (const __attribute__((address_space(1))) unsigned int*)(g),
      (__attribute__((address_space(3))) unsigned int*)(l), 16, 0, 0);
}

// ---------------- packing / conversion kernels (f32 -> bf16) ----------------

__global__ void pack_x(const float* __restrict__ word,
                       const float* __restrict__ tag,
                       const float* __restrict__ rel,
                       unsigned short* __restrict__ xcat) {
  int idx = blockIdx.x * 256 + threadIdx.x;       // N*KPAD
  if (idx >= NROWS * KPAD) return;
  int n = idx / KPAD, c = idx % KPAD;
  float v = 0.f;
  if (c < 300)      v = word[n * 300 + c];
  else if (c < 350) v = tag[n * 50 + (c - 300)];
  else if (c < 400) v = rel[n * 50 + (c - 350)];
  xcat[idx] = f2b(v);
}

__global__ void pack_w(const float* __restrict__ Ww,
                       const float* __restrict__ Wt,
                       const float* __restrict__ Wr,
                       unsigned short* __restrict__ Wcat) {
  int idx = blockIdx.x * 256 + threadIdx.x;       // 2560*KPAD
  if (idx >= GATES * HDIM * KPAD) return;
  int gh = idx / KPAD;
  int c = idx % KPAD;
  float v = 0.f;
  if (c < 300)      v = Ww[gh * 300 + c];
  else if (c < 350) v = Wt[gh * 50 + (c - 300)];
  else if (c < 400) v = Wr[gh * 50 + (c - 350)];
  Wcat[idx] = f2b(v);
}

__global__ void cvt_w4(const float* __restrict__ a, const float* __restrict__ b,
                       const float* __restrict__ c, const float* __restrict__ d,
                       unsigned short* oa, unsigned short* ob,
                       unsigned short* oc, unsigned short* od) {
  const float* in; unsigned short* out;
  switch (blockIdx.y) {
    case 0: in = a; out = oa; break;
    case 1: in = b; out = ob; break;
    case 2: in = c; out = oc; break;
    default: in = d; out = od; break;
  }
  int i = (blockIdx.x * 256 + threadIdx.x) * 4;   // 1310720 elems
  float4 v = *(const float4*)(in + i);
  ushort4 o;
  o.x = f2b(v.x); o.y = f2b(v.y); o.z = f2b(v.z); o.w = f2b(v.w);
  *(ushort4*)(out + i) = o;
}

__global__ void cvt_x2(const float* __restrict__ a, const float* __restrict__ b,
                       unsigned short* oa, unsigned short* ob) {
  const float* in = blockIdx.y ? b : a;
  unsigned short* out = blockIdx.y ? ob : oa;
  int i = (blockIdx.x * 256 + threadIdx.x) * 4;   // 8388608 elems
  float4 v = *(const float4*)(in + i);
  ushort4 o;
  o.x = f2b(v.x); o.y = f2b(v.y); o.z = f2b(v.z); o.w = f2b(v.w);
  *(ushort4*)(out + i) = o;
}

__global__ void pack_bias(const float* __restrict__ bw, const float* __restrict__ bt,
                          const float* __restrict__ br, const float* __restrict__ bh,
                          const float* __restrict__ bl, const float* __restrict__ bhp,
                          const float* __restrict__ bk,
                          float* bias0, float* bias1, float* bias2, float* biasD) {
  int i = blockIdx.x * 256 + threadIdx.x;
  if (i < GATES * HDIM) {
    bias0[i] = bw[i] + bt[i] + br[i];
    bias1[i] = bh[i];
    bias2[i] = bl[i];
    biasD[i] = bhp[i] + bk[i];
  }
}

// ---------------- GEMM: 256x256 tile, BK=32, 8 waves, 2-phase/K-tile ---------
// K-loop identical to round 9 (verified). Coalesced epilogue with STATIC acc
// indexing (h-loop unrolled — round 11's runtime `mib` spilled acc to scratch,
// +335 MB writes). Store mapping: chunk c=v*512+t -> row=c>>5, col16=c&31:
// consecutive lanes write consecutive 16B (1KB contiguous per wave-store).
// MODE 0: Out = tanh(A*W^T + bias); MODE 1: + A2*W2^T + Madd, gate activation.

template<int MODE>
__global__ __launch_bounds__(512, 2) void gemm_big(
    const unsigned short* __restrict__ A1, const unsigned short* __restrict__ A2,
    const unsigned short* __restrict__ W1, const unsigned short* __restrict__ W2,
    const float* __restrict__ bias,
    const unsigned short* __restrict__ Madd,
    unsigned short* __restrict__ Out,
    int aPerGate, int S, int ld)
{
  __shared__ __align__(16) unsigned short smem[32768];   // 64 KB, aliased
  unsigned short* Ab0 = smem;            // staging A [2][8192]
  unsigned short* Bb0 = smem + 16384;    // staging B [2][8192]
  unsigned short* eps = smem;            // epilogue [64][260]

  const int t = threadIdx.x;
  const int row0  = blockIdx.x * 256;
  const int gcol0 = blockIdx.y * 256;          // [0,2560)
  const int g = gcol0 >> 9;
  const size_t aslab = aPerGate ? (size_t)g * NROWS * ld : 0;

  const int wid = t >> 6, l = t & 63;
  const int wrow = (wid >> 2) * 128;
  const int wcol = (wid & 3) * 64;
  const int fr = l & 15, q = l >> 4;

  f32x4 acc[8][4];
#pragma unroll
  for (int mi = 0; mi < 8; ++mi)
#pragma unroll
    for (int ni = 0; ni < 4; ++ni)
      acc[mi][ni] = (f32x4){0.f, 0.f, 0.f, 0.f};

  auto stage = [&](int c, int buf) {
    const unsigned short* Asrc; const unsigned short* Wsrc; int kloc;
    if (MODE == 1 && c >= 16) { Asrc = A2;         Wsrc = W2; kloc = (c - 16) * 32; }
    else                      { Asrc = A1 + aslab; Wsrc = W1; kloc = c * 32; }
#pragma unroll
    for (int j = 0; j < 2; ++j) {
      const int r  = j * 128 + (t >> 2);
      const int sg = ((t & 3) ^ (r & 3)) * 8;
      gload_lds16(Asrc + (size_t)(row0 + r) * ld + kloc + sg,  &Ab0[buf * 8192 + j * 4096 + t * 8]);
      gload_lds16(Wsrc + (size_t)(gcol0 + r) * ld + kloc + sg, &Bb0[buf * 8192 + j * 4096 + t * 8]);
    }
  };

  stage(0, 0);
  asm volatile("s_waitcnt vmcnt(0)" ::: "memory");
  __builtin_amdgcn_s_barrier();

  bf16x8 bq[4];
  for (int s = 0; s < S; ++s) {
    const int buf = s & 1;
#pragma unroll
    for (int p = 0; p < 2; ++p) {
      bf16x8 af[4];
#pragma unroll
      for (int mi = 0; mi < 4; ++mi) {
        const int r = wrow + (p * 4 + mi) * 16 + fr;
        af[mi] = *reinterpret_cast<const bf16x8*>(&Ab0[buf * 8192 + r * 32 + ((q ^ (r & 3)) * 8)]);
      }
      if (p == 0) {
#pragma unroll
        for (int ni = 0; ni < 4; ++ni) {
          const int r = wcol + ni * 16 + fr;
          bq[ni] = *reinterpret_cast<const bf16x8*>(&Bb0[buf * 8192 + r * 32 + ((q ^ (r & 3)) * 8)]);
        }
        if (s + 1 < S) stage(s + 1, buf ^ 1);
      }
      asm volatile("s_waitcnt lgkmcnt(0)" ::: "memory");
      __builtin_amdgcn_sched_barrier(0);
      __builtin_amdgcn_s_setprio(1);
#pragma unroll
      for (int mi = 0; mi < 4; ++mi)
#pragma unroll
        for (int ni = 0; ni < 4; ++ni)
          acc[p * 4 + mi][ni] = __builtin_amdgcn_mfma_f32_16x16x32_bf16(af[mi], bq[ni], acc[p * 4 + mi][ni], 0, 0, 0);
      __builtin_amdgcn_s_setprio(0);
      if (p == 0) __builtin_amdgcn_s_barrier();
    }
    asm volatile("s_waitcnt vmcnt(0)" ::: "memory");
    __builtin_amdgcn_s_barrier();
  }

  // ---- coalesced epilogue: 4 passes of 64 rows through LDS (static indices) --
  const size_t NM = (size_t)NROWS * HDIM;
  unsigned short* outg = Out + (size_t)g * NM;
  const int colbase = gcol0 & 511;
  float bv[4];
#pragma unroll
  for (int ni = 0; ni < 4; ++ni)
    bv[ni] = bias[g * HDIM + colbase + wcol + ni * 16 + fr];

#pragma unroll
  for (int h = 0; h < 4; ++h) {
    __builtin_amdgcn_s_barrier();          // prior read-pass done
    if ((wid >> 2) == (h >> 1)) {          // owning wave-group writes
      const int mib = (h & 1) * 4;         // compile-time after unroll
#pragma unroll
      for (int mi2 = 0; mi2 < 4; ++mi2)
#pragma unroll
        for (int ni = 0; ni < 4; ++ni)
#pragma unroll
          for (int j = 0; j < 4; ++j)
            eps[(mi2 * 16 + q * 4 + j) * 260 + wcol + ni * 16 + fr] =
                f2b(acc[mib + mi2][ni][j] + bv[ni]);
    }
    __builtin_amdgcn_s_barrier();
#pragma unroll
    for (int v = 0; v < 4; ++v) {
      const int c  = v * 512 + t;          // 2048 chunks of 16B
      const int rl = c >> 5;               // 0..63
      const int cc = (c & 31) * 8;         // shorts
      const int gr = row0 + h * 64 + rl;
      bf16x8 pv = *reinterpret_cast<const bf16x8*>(&eps[rl * 260 + cc]);
      bf16x8 ov;
      if (MODE == 1) {
        bf16x8 mv = *reinterpret_cast<const bf16x8*>(
            Madd + (size_t)g * NM + (size_t)gr * HDIM + colbase + cc);
#pragma unroll
        for (int e = 0; e < 8; ++e) {
          float f = b2f((unsigned short)pv[e]) + b2f((unsigned short)mv[e]);
          f = (g < 4) ? fast_sigmoid(f) : fast_tanh(f);
          ov[e] = (short)f2b(f);
        }
      } else {
#pragma unroll
        for (int e = 0; e < 8; ++e)
          ov[e] = (short)f2b(fast_tanh(b2f((unsigned short)pv[e])));
      }
      *reinterpret_cast<bf16x8*>(&outg[(size_t)gr * HDIM + colbase + cc]) = ov;
    }
  }
}

// ---------------- final elementwise combine (f32 q/c_prev, f32 out) ---------

__device__ inline float exb(const uint4& v, int j) {
  unsigned int wd = ((const unsigned int*)&v)[j >> 1];
  return b2f((unsigned short)(wd >> ((j & 1) * 16)));
}

__global__ void combine(const unsigned short* __restrict__ gates,
                        const float* __restrict__ q,
                        const float* __restrict__ cp,
                        float* __restrict__ out) {
  const size_t NM = (size_t)NROWS * HDIM;
  size_t i8 = ((size_t)blockIdx.x * 256 + threadIdx.x) * 8;
  if (i8 >= NM) return;
  uint4 gi = *(const uint4*)(gates + 0 * NM + i8);
  uint4 gf = *(const uint4*)(gates + 1 * NM + i8);
  uint4 gl = *(const uint4*)(gates + 2 * NM + i8);
  uint4 go = *(const uint4*)(gates + 3 * NM + i8);
  uint4 gu = *(const uint4*)(gates + 4 * NM + i8);
  float4 q0 = *(const float4*)(q + i8);
  float4 q1 = *(const float4*)(q + i8 + 4);
  float4 p0 = *(const float4*)(cp + i8);
  float4 p1 = *(const float4*)(cp + i8 + 4);
  float qv[8] = {q0.x, q0.y, q0.z, q0.w, q1.x, q1.y, q1.z, q1.w};
  float pv[8] = {p0.x, p0.y, p0.z, p0.w, p1.x, p1.y, p1.z, p1.w};
  float hv[8], cv[8];
#pragma unroll
  for (int j = 0; j < 8; ++j) {
    float c = exb(gi, j) * exb(gu, j) + exb(gf, j) * qv[j] + exb(gl, j) * pv[j];
    hv[j] = exb(go, j) * fast_tanh(c);
    cv[j] = c;
  }
  *(float4*)(out + i8)      = make_float4(hv[0], hv[1], hv[2], hv[3]);
  *(float4*)(out + i8 + 4)  = make_float4(hv[4], hv[5], hv[6], hv[7]);
  *(float4*)(out + NM + i8)     = make_float4(cv[0], cv[1], cv[2], cv[3]);
  *(float4*)(out + NM + i8 + 4) = make_float4(cv[4], cv[5], cv[6], cv[7]);
}

// ---------------- launch ----------------

extern "C" void kernel_launch(void* const* d_in, const int* in_sizes, int n_in,
                              void* d_out, int out_size, void* d_ws, size_t ws_size,
                              hipStream_t stream) {
  const float* word  = (const float*)d_in[0];
  const float* tag   = (const float*)d_in[1];
  const float* rel   = (const float*)d_in[2];
  const float* kin   = (const float*)d_in[3];
  const float* qin   = (const float*)d_in[4];
  const float* hprev = (const float*)d_in[5];
  const float* cprev = (const float*)d_in[6];
  const float* Ww    = (const float*)d_in[7];
  const float* bw    = (const float*)d_in[8];
  const float* Wt    = (const float*)d_in[9];
  const float* bt    = (const float*)d_in[10];
  const float* Wr    = (const float*)d_in[11];
  const float* br    = (const float*)d_in[12];
  const float* Wh    = (const float*)d_in[13];
  const float* bh    = (const float*)d_in[14];
  const float* Wl    = (const float*)d_in[15];
  const float* bl    = (const float*)d_in[16];
  const float* Whp   = (const float*)d_in[17];
  const float* bhp   = (const float*)d_in[18];
  const float* Wk    = (const float*)d_in[19];
  const float* bk    = (const float*)d_in[20];

  char* ws = (char*)d_ws;
  unsigned short* xcat   = (unsigned short*)(ws);                 // 13,631,488 B
  unsigned short* Wcat   = (unsigned short*)(ws + 13631488);      //  2,129,920 B
  unsigned short* Whb    = (unsigned short*)(ws + 15761408);      //  2,621,440 B
  unsigned short* Wlb    = (unsigned short*)(ws + 18382848);
  unsigned short* Whpb   = (unsigned short*)(ws + 21004288);
  unsigned short* Wkb    = (unsigned short*)(ws + 23625728);
  unsigned short* hprevb = (unsigned short*)(ws + 26247168);      // 16,777,216 B
  unsigned short* kb16   = (unsigned short*)(ws + 43024384);      // 16,777,216 B
  float* bias0           = (float*)(ws + 59801600);
  float* bias1           = (float*)(ws + 59811840);
  float* bias2           = (float*)(ws + 59822080);
  float* biasD           = (float*)(ws + 59832320);
  unsigned short* bufA   = (unsigned short*)(ws + 59842560);      // 83,886,080 B
  unsigned short* bufB   = (unsigned short*)(ws + 143728640);     // 83,886,080 B
  // total: 227,614,720 B

  pack_x<<<26624, 256, 0, stream>>>(word, tag, rel, xcat);
  pack_w<<<4160, 256, 0, stream>>>(Ww, Wt, Wr, Wcat);
  cvt_w4<<<dim3(1280, 4), 256, 0, stream>>>(Wh, Wl, Whp, Wk, Whb, Wlb, Whpb, Wkb);
  cvt_x2<<<dim3(8192, 2), 256, 0, stream>>>(hprev, kin, hprevb, kb16);
  pack_bias<<<10, 256, 0, stream>>>(bw, bt, br, bh, bl, bhp, bk, bias0, bias1, bias2, biasD);

  dim3 grid(NROWS / 256, (GATES * HDIM) / 256);   // 64 x 10
  // h0 = tanh(xcat W0^T + b0)            K=416 (13 tiles)
  gemm_big<0><<<grid, 512, 0, stream>>>(xcat, nullptr, Wcat, nullptr, bias0, nullptr, bufA, 0, 13, KPAD);
  // h1 = tanh(h0 Whid^T + bhid)          K=512
  gemm_big<0><<<grid, 512, 0, stream>>>(bufA, nullptr, Whb, nullptr, bias1, nullptr, bufB, 1, 16, HDIM);
  // m = tanh(h1 Wlast^T + blast)         K=512
  gemm_big<0><<<grid, 512, 0, stream>>>(bufB, nullptr, Wlb, nullptr, bias2, nullptr, bufA, 1, 16, HDIM);
  // gates = act(hprev Whp^T + k Wk^T + biasD + m)    K=1024
  gemm_big<1><<<grid, 512, 0, stream>>>(hprevb, kb16, Whpb, Wkb, biasD, bufA, bufB, 0, 32, HDIM);
  // c = i*u + f_down*q + f_left*c_prev ; h = o*tanh(c)
  combine<<<4096, 256, 0, stream>>>(bufB, qin, cprev, (float*)d_out);
}

// Round 13
// 480.036 us; speedup vs baseline: 1.6329x; 1.0117x over previous
//
#include <hip/hip_runtime.h>
#include <math.h>

#define NROWS 16384
#define GATES 5
#define HDIM 512
#define KPAD 416   // stage-1 K: 400 real cols padded to 13*32

using bf16x8 = __attribute__((ext_vector_type(8))) short;
using f32x4  = __attribute__((ext_vector_type(4))) float;

__device__ inline float b2f(unsigned short s) {
  unsigned int u = ((unsigned int)s) << 16;
  return __builtin_bit_cast(float, u);
}
__device__ inline unsigned short f2b(float f) {
  unsigned int u = __builtin_bit_cast(unsigned int, f);
  u += 0x7fffu + ((u >> 16) & 1u);   // RNE
  return (unsigned short)(u >> 16);
}

__device__ inline float fast_sigmoid(float x) {
  float t = __builtin_amdgcn_exp2f(-1.4426950408889634f * x);
  return __builtin_amdgcn_rcpf(1.0f + t);
}
__device__ inline float fast_tanh(float x) {
  float t = __builtin_amdgcn_exp2f(2.8853900817779268f * x);
  return 1.0f - 2.0f * __builtin_amdgcn_rcpf(1.0f + t);
}

__device__ inline void gload_lds16(const unsigned short* g, unsigned short* l) {
  __builtin_amdgcn_global_load_lds(
      (const __attribute__((address_space(1))) unsigned int*)(g),
      (__attribute__((address_space(3))) unsigned int*)(l), 16, 0, 0);
}

// ---------------- packing / conversion kernels (f32 -> bf16) ----------------

__global__ void pack_x(const float* __restrict__ word,
                       const float* __restrict__ tag,
                       const float* __restrict__ rel,
                       unsigned short* __restrict__ xcat) {
  int idx = blockIdx.x * 256 + threadIdx.x;       // N*KPAD
  if (idx >= NROWS * KPAD) return;
  int n = idx / KPAD, c = idx % KPAD;
  float v = 0.f;
  if (c < 300)      v = word[n * 300 + c];
  else if (c < 350) v = tag[n * 50 + (c - 300)];
  else if (c < 400) v = rel[n * 50 + (c - 350)];
  xcat[idx] = f2b(v);
}

__global__ void pack_w(const float* __restrict__ Ww,
                       const float* __restrict__ Wt,
                       const float* __restrict__ Wr,
                       unsigned short* __restrict__ Wcat) {
  int idx = blockIdx.x * 256 + threadIdx.x;       // 2560*KPAD
  if (idx >= GATES * HDIM * KPAD) return;
  int gh = idx / KPAD;
  int c = idx % KPAD;
  float v = 0.f;
  if (c < 300)      v = Ww[gh * 300 + c];
  else if (c < 350) v = Wt[gh * 50 + (c - 300)];
  else if (c < 400) v = Wr[gh * 50 + (c - 350)];
  Wcat[idx] = f2b(v);
}

__global__ void cvt_w4(const float* __restrict__ a, const float* __restrict__ b,
                       const float* __restrict__ c, const float* __restrict__ d,
                       unsigned short* oa, unsigned short* ob,
                       unsigned short* oc, unsigned short* od) {
  const float* in; unsigned short* out;
  switch (blockIdx.y) {
    case 0: in = a; out = oa; break;
    case 1: in = b; out = ob; break;
    case 2: in = c; out = oc; break;
    default: in = d; out = od; break;
  }
  int i = (blockIdx.x * 256 + threadIdx.x) * 4;   // 1310720 elems
  float4 v = *(const float4*)(in + i);
  ushort4 o;
  o.x = f2b(v.x); o.y = f2b(v.y); o.z = f2b(v.z); o.w = f2b(v.w);
  *(ushort4*)(out + i) = o;
}

__global__ void cvt_x2(const float* __restrict__ a, const float* __restrict__ b,
                       unsigned short* oa, unsigned short* ob) {
  const float* in = blockIdx.y ? b : a;
  unsigned short* out = blockIdx.y ? ob : oa;
  int i = (blockIdx.x * 256 + threadIdx.x) * 4;   // 8388608 elems
  float4 v = *(const float4*)(in + i);
  ushort4 o;
  o.x = f2b(v.x); o.y = f2b(v.y); o.z = f2b(v.z); o.w = f2b(v.w);
  *(ushort4*)(out + i) = o;
}

__global__ void pack_bias(const float* __restrict__ bw, const float* __restrict__ bt,
                          const float* __restrict__ br, const float* __restrict__ bh,
                          const float* __restrict__ bl, const float* __restrict__ bhp,
                          const float* __restrict__ bk,
                          float* bias0, float* bias1, float* bias2, float* biasD) {
  int i = blockIdx.x * 256 + threadIdx.x;
  if (i < GATES * HDIM) {
    bias0[i] = bw[i] + bt[i] + br[i];
    bias1[i] = bh[i];
    bias2[i] = bl[i];
    biasD[i] = bhp[i] + bk[i];
  }
}

// ---------------- GEMM: 256x256 tile, BK=32, 8 waves ------------------------
// K-loop (round 13): counted vmcnt, 2 barriers/tile. Per tile s:
//   stage(s+1) -> s_waitcnt vmcnt(4)  [tile-s landed; s+1's 4 loads stay in
//   flight across the whole tile-s compute] -> barrier -> MFMA (2 sub-phases,
//   no mid barrier, no sched pin) -> barrier [protects buf from stage(s+2)].
// Epilogue (round 12, verified): LDS-staged coalesced writes, static indices.
// MODE 0: Out = tanh(A*W^T + bias); MODE 1: + A2*W2^T + Madd, gate activation.

template<int MODE>
__global__ __launch_bounds__(512, 2) void gemm_big(
    const unsigned short* __restrict__ A1, const unsigned short* __restrict__ A2,
    const unsigned short* __restrict__ W1, const unsigned short* __restrict__ W2,
    const float* __restrict__ bias,
    const unsigned short* __restrict__ Madd,
    unsigned short* __restrict__ Out,
    int aPerGate, int S, int ld)
{
  __shared__ __align__(16) unsigned short smem[32768];   // 64 KB, aliased
  unsigned short* Ab0 = smem;            // staging A [2][8192]
  unsigned short* Bb0 = smem + 16384;    // staging B [2][8192]
  unsigned short* eps = smem;            // epilogue [64][260]

  const int t = threadIdx.x;
  const int row0  = blockIdx.x * 256;
  const int gcol0 = blockIdx.y * 256;          // [0,2560)
  const int g = gcol0 >> 9;
  const size_t aslab = aPerGate ? (size_t)g * NROWS * ld : 0;

  const int wid = t >> 6, l = t & 63;
  const int wrow = (wid >> 2) * 128;
  const int wcol = (wid & 3) * 64;
  const int fr = l & 15, q = l >> 4;

  f32x4 acc[8][4];
#pragma unroll
  for (int mi = 0; mi < 8; ++mi)
#pragma unroll
    for (int ni = 0; ni < 4; ++ni)
      acc[mi][ni] = (f32x4){0.f, 0.f, 0.f, 0.f};

  auto stage = [&](int c, int buf) {
    const unsigned short* Asrc; const unsigned short* Wsrc; int kloc;
    if (MODE == 1 && c >= 16) { Asrc = A2;         Wsrc = W2; kloc = (c - 16) * 32; }
    else                      { Asrc = A1 + aslab; Wsrc = W1; kloc = c * 32; }
#pragma unroll
    for (int j = 0; j < 2; ++j) {
      const int r  = j * 128 + (t >> 2);
      const int sg = ((t & 3) ^ (r & 3)) * 8;
      gload_lds16(Asrc + (size_t)(row0 + r) * ld + kloc + sg,  &Ab0[buf * 8192 + j * 4096 + t * 8]);
      gload_lds16(Wsrc + (size_t)(gcol0 + r) * ld + kloc + sg, &Bb0[buf * 8192 + j * 4096 + t * 8]);
    }
  };

  stage(0, 0);

  for (int s = 0; s < S; ++s) {
    const int buf = s & 1;
    if (s + 1 < S) {
      stage(s + 1, buf ^ 1);     // issue next tile first — flies under compute
      asm volatile("s_waitcnt vmcnt(4)" ::: "memory");   // tile-s landed only
    } else {
      asm volatile("s_waitcnt vmcnt(0)" ::: "memory");
    }
    __builtin_amdgcn_s_barrier();

    bf16x8 bq[4];
#pragma unroll
    for (int ni = 0; ni < 4; ++ni) {
      const int r = wcol + ni * 16 + fr;
      bq[ni] = *reinterpret_cast<const bf16x8*>(&Bb0[buf * 8192 + r * 32 + ((q ^ (r & 3)) * 8)]);
    }
#pragma unroll
    for (int p = 0; p < 2; ++p) {
      bf16x8 af[4];
#pragma unroll
      for (int mi = 0; mi < 4; ++mi) {
        const int r = wrow + (p * 4 + mi) * 16 + fr;
        af[mi] = *reinterpret_cast<const bf16x8*>(&Ab0[buf * 8192 + r * 32 + ((q ^ (r & 3)) * 8)]);
      }
      __builtin_amdgcn_s_setprio(1);
#pragma unroll
      for (int mi = 0; mi < 4; ++mi)
#pragma unroll
        for (int ni = 0; ni < 4; ++ni)
          acc[p * 4 + mi][ni] = __builtin_amdgcn_mfma_f32_16x16x32_bf16(af[mi], bq[ni], acc[p * 4 + mi][ni], 0, 0, 0);
      __builtin_amdgcn_s_setprio(0);
    }
    __builtin_amdgcn_s_barrier();   // all waves done reading buf -> stage(s+2) safe
  }

  // ---- coalesced epilogue: 4 passes of 64 rows through LDS (static indices) --
  const size_t NM = (size_t)NROWS * HDIM;
  unsigned short* outg = Out + (size_t)g * NM;
  const int colbase = gcol0 & 511;
  float bv[4];
#pragma unroll
  for (int ni = 0; ni < 4; ++ni)
    bv[ni] = bias[g * HDIM + colbase + wcol + ni * 16 + fr];

#pragma unroll
  for (int h = 0; h < 4; ++h) {
    __builtin_amdgcn_s_barrier();          // prior read-pass done
    if ((wid >> 2) == (h >> 1)) {          // owning wave-group writes
      const int mib = (h & 1) * 4;         // compile-time after unroll
#pragma unroll
      for (int mi2 = 0; mi2 < 4; ++mi2)
#pragma unroll
        for (int ni = 0; ni < 4; ++ni)
#pragma unroll
          for (int j = 0; j < 4; ++j)
            eps[(mi2 * 16 + q * 4 + j) * 260 + wcol + ni * 16 + fr] =
                f2b(acc[mib + mi2][ni][j] + bv[ni]);
    }
    __builtin_amdgcn_s_barrier();
#pragma unroll
    for (int v = 0; v < 4; ++v) {
      const int c  = v * 512 + t;          // 2048 chunks of 16B
      const int rl = c >> 5;               // 0..63
      const int cc = (c & 31) * 8;         // shorts
      const int gr = row0 + h * 64 + rl;
      bf16x8 pv = *reinterpret_cast<const bf16x8*>(&eps[rl * 260 + cc]);
      bf16x8 ov;
      if (MODE == 1) {
        bf16x8 mv = *reinterpret_cast<const bf16x8*>(
            Madd + (size_t)g * NM + (size_t)gr * HDIM + colbase + cc);
#pragma unroll
        for (int e = 0; e < 8; ++e) {
          float f = b2f((unsigned short)pv[e]) + b2f((unsigned short)mv[e]);
          f = (g < 4) ? fast_sigmoid(f) : fast_tanh(f);
          ov[e] = (short)f2b(f);
        }
      } else {
#pragma unroll
        for (int e = 0; e < 8; ++e)
          ov[e] = (short)f2b(fast_tanh(b2f((unsigned short)pv[e])));
      }
      *reinterpret_cast<bf16x8*>(&outg[(size_t)gr * HDIM + colbase + cc]) = ov;
    }
  }
}

// ---------------- final elementwise combine (f32 q/c_prev, f32 out) ---------

__device__ inline float exb(const uint4& v, int j) {
  unsigned int wd = ((const unsigned int*)&v)[j >> 1];
  return b2f((unsigned short)(wd >> ((j & 1) * 16)));
}

__global__ void combine(const unsigned short* __restrict__ gates,
                        const float* __restrict__ q,
                        const float* __restrict__ cp,
                        float* __restrict__ out) {
  const size_t NM = (size_t)NROWS * HDIM;
  size_t i8 = ((size_t)blockIdx.x * 256 + threadIdx.x) * 8;
  if (i8 >= NM) return;
  uint4 gi = *(const uint4*)(gates + 0 * NM + i8);
  uint4 gf = *(const uint4*)(gates + 1 * NM + i8);
  uint4 gl = *(const uint4*)(gates + 2 * NM + i8);
  uint4 go = *(const uint4*)(gates + 3 * NM + i8);
  uint4 gu = *(const uint4*)(gates + 4 * NM + i8);
  float4 q0 = *(const float4*)(q + i8);
  float4 q1 = *(const float4*)(q + i8 + 4);
  float4 p0 = *(const float4*)(cp + i8);
  float4 p1 = *(const float4*)(cp + i8 + 4);
  float qv[8] = {q0.x, q0.y, q0.z, q0.w, q1.x, q1.y, q1.z, q1.w};
  float pv[8] = {p0.x, p0.y, p0.z, p0.w, p1.x, p1.y, p1.z, p1.w};
  float hv[8], cv[8];
#pragma unroll
  for (int j = 0; j < 8; ++j) {
    float c = exb(gi, j) * exb(gu, j) + exb(gf, j) * qv[j] + exb(gl, j) * pv[j];
    hv[j] = exb(go, j) * fast_tanh(c);
    cv[j] = c;
  }
  *(float4*)(out + i8)      = make_float4(hv[0], hv[1], hv[2], hv[3]);
  *(float4*)(out + i8 + 4)  = make_float4(hv[4], hv[5], hv[6], hv[7]);
  *(float4*)(out + NM + i8)     = make_float4(cv[0], cv[1], cv[2], cv[3]);
  *(float4*)(out + NM + i8 + 4) = make_float4(cv[4], cv[5], cv[6], cv[7]);
}

// ---------------- launch ----------------

extern "C" void kernel_launch(void* const* d_in, const int* in_sizes, int n_in,
                              void* d_out, int out_size, void* d_ws, size_t ws_size,
                              hipStream_t stream) {
  const float* word  = (const float*)d_in[0];
  const float* tag   = (const float*)d_in[1];
  const float* rel   = (const float*)d_in[2];
  const float* kin   = (const float*)d_in[3];
  const float* qin   = (const float*)d_in[4];
  const float* hprev = (const float*)d_in[5];
  const float* cprev = (const float*)d_in[6];
  const float* Ww    = (const float*)d_in[7];
  const float* bw    = (const float*)d_in[8];
  const float* Wt    = (const float*)d_in[9];
  const float* bt    = (const float*)d_in[10];
  const float* Wr    = (const float*)d_in[11];
  const float* br    = (const float*)d_in[12];
  const float* Wh    = (const float*)d_in[13];
  const float* bh    = (const float*)d_in[14];
  const float* Wl    = (const float*)d_in[15];
  const float* bl    = (const float*)d_in[16];
  const float* Whp   = (const float*)d_in[17];
  const float* bhp   = (const float*)d_in[18];
  const float* Wk    = (const float*)d_in[19];
  const float* bk    = (const float*)d_in[20];

  char* ws = (char*)d_ws;
  unsigned short* xcat   = (unsigned short*)(ws);                 // 13,631,488 B
  unsigned short* Wcat   = (unsigned short*)(ws + 13631488);      //  2,129,920 B
  unsigned short* Whb    = (unsigned short*)(ws + 15761408);      //  2,621,440 B
  unsigned short* Wlb    = (unsigned short*)(ws + 18382848);
  unsigned short* Whpb   = (unsigned short*)(ws + 21004288);
  unsigned short* Wkb    = (unsigned short*)(ws + 23625728);
  unsigned short* hprevb = (unsigned short*)(ws + 26247168);      // 16,777,216 B
  unsigned short* kb16   = (unsigned short*)(ws + 43024384);      // 16,777,216 B
  float* bias0           = (float*)(ws + 59801600);
  float* bias1           = (float*)(ws + 59811840);
  float* bias2           = (float*)(ws + 59822080);
  float* biasD           = (float*)(ws + 59832320);
  unsigned short* bufA   = (unsigned short*)(ws + 59842560);      // 83,886,080 B
  unsigned short* bufB   = (unsigned short*)(ws + 143728640);     // 83,886,080 B
  // total: 227,614,720 B

  pack_x<<<26624, 256, 0, stream>>>(word, tag, rel, xcat);
  pack_w<<<4160, 256, 0, stream>>>(Ww, Wt, Wr, Wcat);
  cvt_w4<<<dim3(1280, 4), 256, 0, stream>>>(Wh, Wl, Whp, Wk, Whb, Wlb, Whpb, Wkb);
  cvt_x2<<<dim3(8192, 2), 256, 0, stream>>>(hprev, kin, hprevb, kb16);
  pack_bias<<<10, 256, 0, stream>>>(bw, bt, br, bh, bl, bhp, bk, bias0, bias1, bias2, biasD);

  dim3 grid(NROWS / 256, (GATES * HDIM) / 256);   // 64 x 10
  // h0 = tanh(xcat W0^T + b0)            K=416 (13 tiles)
  gemm_big<0><<<grid, 512, 0, stream>>>(xcat, nullptr, Wcat, nullptr, bias0, nullptr, bufA, 0, 13, KPAD);
  // h1 = tanh(h0 Whid^T + bhid)          K=512
  gemm_big<0><<<grid, 512, 0, stream>>>(bufA, nullptr, Whb, nullptr, bias1, nullptr, bufB, 1, 16, HDIM);
  // m = tanh(h1 Wlast^T + blast)         K=512
  gemm_big<0><<<grid, 512, 0, stream>>>(bufB, nullptr, Wlb, nullptr, bias2, nullptr, bufA, 1, 16, HDIM);
  // gates = act(hprev Whp^T + k Wk^T + biasD + m)    K=1024
  gemm_big<1><<<grid, 512, 0, stream>>>(hprevb, kb16, Whpb, Wkb, biasD, bufA, bufB, 0, 32, HDIM);
  // c = i*u + f_down*q + f_left*c_prev ; h = o*tanh(c)
  combine<<<4096, 256, 0, stream>>>(bufB, qin, cprev, (float*)d_out);
}

// Round 14
// 400.746 us; speedup vs baseline: 1.9560x; 1.1979x over previous
//
#include <hip/hip_runtime.h>
#include <math.h>

#define NROWS 16384
#define GATES 5
#define HDIM 512
#define KPAD 416   // stage-1 K: 400 real cols padded to 13*32

using bf16x8 = __attribute__((ext_vector_type(8))) short;
using f32x4  = __attribute__((ext_vector_type(4))) float;

__device__ inline float b2f(unsigned short s) {
  unsigned int u = ((unsigned int)s) << 16;
  return __builtin_bit_cast(float, u);
}
__device__ inline unsigned short f2b(float f) {
  unsigned int u = __builtin_bit_cast(unsigned int, f);
  u += 0x7fffu + ((u >> 16) & 1u);   // RNE
  return (unsigned short)(u >> 16);
}

__device__ inline float fast_sigmoid(float x) {
  float t = __builtin_amdgcn_exp2f(-1.4426950408889634f * x);
  return __builtin_amdgcn_rcpf(1.0f + t);
}
__device__ inline float fast_tanh(float x) {
  float t = __builtin_amdgcn_exp2f(2.8853900817779268f * x);
  return 1.0f - 2.0f * __builtin_amdgcn_rcpf(1.0f + t);
}

__device__ inline void gload_lds16(const unsigned short* g, unsigned short* l) {
  __builtin_amdgcn_global_load_lds(
      (const __attribute__((address_space(1))) unsigned int*)(g),
      (__attribute__((address_space(3))) unsigned int*)(l), 16, 0, 0);
}

// ---------------- packing / conversion kernels (f32 -> bf16) ----------------

__global__ void pack_x(const float* __restrict__ word,
                       const float* __restrict__ tag,
                       const float* __restrict__ rel,
                       unsigned short* __restrict__ xcat) {
  int idx = blockIdx.x * 256 + threadIdx.x;       // N*KPAD
  if (idx >= NROWS * KPAD) return;
  int n = idx / KPAD, c = idx % KPAD;
  float v = 0.f;
  if (c < 300)      v = word[n * 300 + c];
  else if (c < 350) v = tag[n * 50 + (c - 300)];
  else if (c < 400) v = rel[n * 50 + (c - 350)];
  xcat[idx] = f2b(v);
}

__global__ void pack_w(const float* __restrict__ Ww,
                       const float* __restrict__ Wt,
                       const float* __restrict__ Wr,
                       unsigned short* __restrict__ Wcat) {
  int idx = blockIdx.x * 256 + threadIdx.x;       // 2560*KPAD
  if (idx >= GATES * HDIM * KPAD) return;
  int gh = idx / KPAD;
  int c = idx % KPAD;
  float v = 0.f;
  if (c < 300)      v = Ww[gh * 300 + c];
  else if (c < 350) v = Wt[gh * 50 + (c - 300)];
  else if (c < 400) v = Wr[gh * 50 + (c - 350)];
  Wcat[idx] = f2b(v);
}

__global__ void cvt_w4(const float* __restrict__ a, const float* __restrict__ b,
                       const float* __restrict__ c, const float* __restrict__ d,
                       unsigned short* oa, unsigned short* ob,
                       unsigned short* oc, unsigned short* od) {
  const float* in; unsigned short* out;
  switch (blockIdx.y) {
    case 0: in = a; out = oa; break;
    case 1: in = b; out = ob; break;
    case 2: in = c; out = oc; break;
    default: in = d; out = od; break;
  }
  int i = (blockIdx.x * 256 + threadIdx.x) * 4;   // 1310720 elems
  float4 v = *(const float4*)(in + i);
  ushort4 o;
  o.x = f2b(v.x); o.y = f2b(v.y); o.z = f2b(v.z); o.w = f2b(v.w);
  *(ushort4*)(out + i) = o;
}

__global__ void cvt_x2(const float* __restrict__ a, const float* __restrict__ b,
                       unsigned short* oa, unsigned short* ob) {
  const float* in = blockIdx.y ? b : a;
  unsigned short* out = blockIdx.y ? ob : oa;
  int i = (blockIdx.x * 256 + threadIdx.x) * 4;   // 8388608 elems
  float4 v = *(const float4*)(in + i);
  ushort4 o;
  o.x = f2b(v.x); o.y = f2b(v.y); o.z = f2b(v.z); o.w = f2b(v.w);
  *(ushort4*)(out + i) = o;
}

__global__ void pack_bias(const float* __restrict__ bw, const float* __restrict__ bt,
                          const float* __restrict__ br, const float* __restrict__ bh,
                          const float* __restrict__ bl, const float* __restrict__ bhp,
                          const float* __restrict__ bk,
                          float* bias0, float* bias1, float* bias2, float* biasD) {
  int i = blockIdx.x * 256 + threadIdx.x;
  if (i < GATES * HDIM) {
    bias0[i] = bw[i] + bt[i] + br[i];
    bias1[i] = bh[i];
    bias2[i] = bl[i];
    biasD[i] = bhp[i] + bk[i];
  }
}

// ---------------- GEMM: 256x128 tile, BK=32, 8 waves ------------------------
// Round 14: BN=128 (acc[8][2]=64 regs -> lower unified reg/wave, smaller
// T_block, grid 1280 = exact multiple of resident blocks -> no tail round) +
// XCD-aware bid swizzle, col-fastest (A row-panel L2-reuse x20 per XCD).
// K-loop: counted vmcnt (3 loads/stage), 2 barriers/tile (round 13 verified).
// Epilogue: LDS-staged coalesced writes, static indices (round 12 verified).
// MODE 0: Out = tanh(A*W^T + bias); MODE 1: + A2*W2^T + Madd, gate activation.

template<int MODE>
__global__ __launch_bounds__(512, 2) void gemm_big(
    const unsigned short* __restrict__ A1, const unsigned short* __restrict__ A2,
    const unsigned short* __restrict__ W1, const unsigned short* __restrict__ W2,
    const float* __restrict__ bias,
    const unsigned short* __restrict__ Madd,
    unsigned short* __restrict__ Out,
    int aPerGate, int S, int ld)
{
  __shared__ __align__(16) unsigned short smem[24576];   // 48 KB, aliased
  unsigned short* Ab0 = smem;            // staging A [2][8192]
  unsigned short* Bb0 = smem + 16384;    // staging B [2][4096]
  unsigned short* eps = smem;            // epilogue [64][132]

  // XCD swizzle: 1280 blocks, 8 XCDs, 160 per chunk; col fastest within chunk
  const int bid = (int)blockIdx.x;
  const int swz = (bid & 7) * 160 + (bid >> 3);
  const int col = swz % 20, rowt = swz / 20;
  const int row0  = rowt * 256;
  const int gcol0 = col * 128;                 // [0,2560)
  const int g = gcol0 >> 9;
  const size_t aslab = aPerGate ? (size_t)g * NROWS * ld : 0;

  const int t = threadIdx.x;
  const int wid = t >> 6, l = t & 63;
  const int wrow = (wid >> 2) * 128;           // 2 M-groups
  const int wcol = (wid & 3) * 32;             // 4 N-groups x 32 cols
  const int fr = l & 15, q = l >> 4;

  f32x4 acc[8][2];
#pragma unroll
  for (int mi = 0; mi < 8; ++mi)
#pragma unroll
    for (int ni = 0; ni < 2; ++ni)
      acc[mi][ni] = (f32x4){0.f, 0.f, 0.f, 0.f};

  // staging: A 2 issues (rows j*128+(t>>2)), B 1 issue (rows t>>2); dst linear
  auto stage = [&](int c, int buf) {
    const unsigned short* Asrc; const unsigned short* Wsrc; int kloc;
    if (MODE == 1 && c >= 16) { Asrc = A2;         Wsrc = W2; kloc = (c - 16) * 32; }
    else                      { Asrc = A1 + aslab; Wsrc = W1; kloc = c * 32; }
    const int rb = t >> 2;
    const int sg = ((t & 3) ^ (rb & 3)) * 8;
#pragma unroll
    for (int j = 0; j < 2; ++j) {
      const int r = j * 128 + rb;
      const int sgj = ((t & 3) ^ (r & 3)) * 8;
      gload_lds16(Asrc + (size_t)(row0 + r) * ld + kloc + sgj, &Ab0[buf * 8192 + j * 4096 + t * 8]);
    }
    gload_lds16(Wsrc + (size_t)(gcol0 + rb) * ld + kloc + sg, &Bb0[buf * 4096 + t * 8]);
  };

  stage(0, 0);

  for (int s = 0; s < S; ++s) {
    const int buf = s & 1;
    if (s + 1 < S) {
      stage(s + 1, buf ^ 1);     // next tile flies under this tile's compute
      asm volatile("s_waitcnt vmcnt(3)" ::: "memory");   // tile-s landed only
    } else {
      asm volatile("s_waitcnt vmcnt(0)" ::: "memory");
    }
    __builtin_amdgcn_s_barrier();

    bf16x8 bq[2];
#pragma unroll
    for (int ni = 0; ni < 2; ++ni) {
      const int r = wcol + ni * 16 + fr;
      bq[ni] = *reinterpret_cast<const bf16x8*>(&Bb0[buf * 4096 + r * 32 + ((q ^ (r & 3)) * 8)]);
    }
#pragma unroll
    for (int p = 0; p < 2; ++p) {
      bf16x8 af[4];
#pragma unroll
      for (int mi = 0; mi < 4; ++mi) {
        const int r = wrow + (p * 4 + mi) * 16 + fr;
        af[mi] = *reinterpret_cast<const bf16x8*>(&Ab0[buf * 8192 + r * 32 + ((q ^ (r & 3)) * 8)]);
      }
      __builtin_amdgcn_s_setprio(1);
#pragma unroll
      for (int mi = 0; mi < 4; ++mi)
#pragma unroll
        for (int ni = 0; ni < 2; ++ni)
          acc[p * 4 + mi][ni] = __builtin_amdgcn_mfma_f32_16x16x32_bf16(af[mi], bq[ni], acc[p * 4 + mi][ni], 0, 0, 0);
      __builtin_amdgcn_s_setprio(0);
    }
    __builtin_amdgcn_s_barrier();   // all waves done reading buf -> stage(s+2) safe
  }

  // ---- coalesced epilogue: 4 passes of 64 rows x 128 cols through LDS -------
  const size_t NM = (size_t)NROWS * HDIM;
  unsigned short* outg = Out + (size_t)g * NM;
  const int colbase = gcol0 & 511;
  float bv[2];
#pragma unroll
  for (int ni = 0; ni < 2; ++ni)
    bv[ni] = bias[g * HDIM + colbase + wcol + ni * 16 + fr];

#pragma unroll
  for (int h = 0; h < 4; ++h) {
    __builtin_amdgcn_s_barrier();          // prior read-pass done
    if ((wid >> 2) == (h >> 1)) {          // owning wave-group writes
      const int mib = (h & 1) * 4;         // compile-time after unroll
#pragma unroll
      for (int mi2 = 0; mi2 < 4; ++mi2)
#pragma unroll
        for (int ni = 0; ni < 2; ++ni)
#pragma unroll
          for (int j = 0; j < 4; ++j)
            eps[(mi2 * 16 + q * 4 + j) * 132 + wcol + ni * 16 + fr] =
                f2b(acc[mib + mi2][ni][j] + bv[ni]);
    }
    __builtin_amdgcn_s_barrier();
#pragma unroll
    for (int v = 0; v < 2; ++v) {
      const int c  = v * 512 + t;          // 1024 chunks of 16B
      const int rl = c >> 4;               // 0..63
      const int cc = (c & 15) * 8;         // shorts, 0..120
      const int gr = row0 + h * 64 + rl;
      bf16x8 pv = *reinterpret_cast<const bf16x8*>(&eps[rl * 132 + cc]);
      bf16x8 ov;
      if (MODE == 1) {
        bf16x8 mv = *reinterpret_cast<const bf16x8*>(
            Madd + (size_t)g * NM + (size_t)gr * HDIM + colbase + cc);
#pragma unroll
        for (int e = 0; e < 8; ++e) {
          float f = b2f((unsigned short)pv[e]) + b2f((unsigned short)mv[e]);
          f = (g < 4) ? fast_sigmoid(f) : fast_tanh(f);
          ov[e] = (short)f2b(f);
        }
      } else {
#pragma unroll
        for (int e = 0; e < 8; ++e)
          ov[e] = (short)f2b(fast_tanh(b2f((unsigned short)pv[e])));
      }
      *reinterpret_cast<bf16x8*>(&outg[(size_t)gr * HDIM + colbase + cc]) = ov;
    }
  }
}

// ---------------- final elementwise combine (f32 q/c_prev, f32 out) ---------

__device__ inline float exb(const uint4& v, int j) {
  unsigned int wd = ((const unsigned int*)&v)[j >> 1];
  return b2f((unsigned short)(wd >> ((j & 1) * 16)));
}

__global__ void combine(const unsigned short* __restrict__ gates,
                        const float* __restrict__ q,
                        const float* __restrict__ cp,
                        float* __restrict__ out) {
  const size_t NM = (size_t)NROWS * HDIM;
  size_t i8 = ((size_t)blockIdx.x * 256 + threadIdx.x) * 8;
  if (i8 >= NM) return;
  uint4 gi = *(const uint4*)(gates + 0 * NM + i8);
  uint4 gf = *(const uint4*)(gates + 1 * NM + i8);
  uint4 gl = *(const uint4*)(gates + 2 * NM + i8);
  uint4 go = *(const uint4*)(gates + 3 * NM + i8);
  uint4 gu = *(const uint4*)(gates + 4 * NM + i8);
  float4 q0 = *(const float4*)(q + i8);
  float4 q1 = *(const float4*)(q + i8 + 4);
  float4 p0 = *(const float4*)(cp + i8);
  float4 p1 = *(const float4*)(cp + i8 + 4);
  float qv[8] = {q0.x, q0.y, q0.z, q0.w, q1.x, q1.y, q1.z, q1.w};
  float pv[8] = {p0.x, p0.y, p0.z, p0.w, p1.x, p1.y, p1.z, p1.w};
  float hv[8], cv[8];
#pragma unroll
  for (int j = 0; j < 8; ++j) {
    float c = exb(gi, j) * exb(gu, j) + exb(gf, j) * qv[j] + exb(gl, j) * pv[j];
    hv[j] = exb(go, j) * fast_tanh(c);
    cv[j] = c;
  }
  *(float4*)(out + i8)      = make_float4(hv[0], hv[1], hv[2], hv[3]);
  *(float4*)(out + i8 + 4)  = make_float4(hv[4], hv[5], hv[6], hv[7]);
  *(float4*)(out + NM + i8)     = make_float4(cv[0], cv[1], cv[2], cv[3]);
  *(float4*)(out + NM + i8 + 4) = make_float4(cv[4], cv[5], cv[6], cv[7]);
}

// ---------------- launch ----------------

extern "C" void kernel_launch(void* const* d_in, const int* in_sizes, int n_in,
                              void* d_out, int out_size, void* d_ws, size_t ws_size,
                              hipStream_t stream) {
  const float* word  = (const float*)d_in[0];
  const float* tag   = (const float*)d_in[1];
  const float* rel   = (const float*)d_in[2];
  const float* kin   = (const float*)d_in[3];
  const float* qin   = (const float*)d_in[4];
  const float* hprev = (const float*)d_in[5];
  const float* cprev = (const float*)d_in[6];
  const float* Ww    = (const float*)d_in[7];
  const float* bw    = (const float*)d_in[8];
  const float* Wt    = (const float*)d_in[9];
  const float* bt    = (const float*)d_in[10];
  const float* Wr    = (const float*)d_in[11];
  const float* br    = (const float*)d_in[12];
  const float* Wh    = (const float*)d_in[13];
  const float* bh    = (const float*)d_in[14];
  const float* Wl    = (const float*)d_in[15];
  const float* bl    = (const float*)d_in[16];
  const float* Whp   = (const float*)d_in[17];
  const float* bhp   = (const float*)d_in[18];
  const float* Wk    = (const float*)d_in[19];
  const float* bk    = (const float*)d_in[20];

  char* ws = (char*)d_ws;
  unsigned short* xcat   = (unsigned short*)(ws);                 // 13,631,488 B
  unsigned short* Wcat   = (unsigned short*)(ws + 13631488);      //  2,129,920 B
  unsigned short* Whb    = (unsigned short*)(ws + 15761408);      //  2,621,440 B
  unsigned short* Wlb    = (unsigned short*)(ws + 18382848);
  unsigned short* Whpb   = (unsigned short*)(ws + 21004288);
  unsigned short* Wkb    = (unsigned short*)(ws + 23625728);
  unsigned short* hprevb = (unsigned short*)(ws + 26247168);      // 16,777,216 B
  unsigned short* kb16   = (unsigned short*)(ws + 43024384);      // 16,777,216 B
  float* bias0           = (float*)(ws + 59801600);
  float* bias1           = (float*)(ws + 59811840);
  float* bias2           = (float*)(ws + 59822080);
  float* biasD           = (float*)(ws + 59832320);
  unsigned short* bufA   = (unsigned short*)(ws + 59842560);      // 83,886,080 B
  unsigned short* bufB   = (unsigned short*)(ws + 143728640);     // 83,886,080 B
  // total: 227,614,720 B

  pack_x<<<26624, 256, 0, stream>>>(word, tag, rel, xcat);
  pack_w<<<4160, 256, 0, stream>>>(Ww, Wt, Wr, Wcat);
  cvt_w4<<<dim3(1280, 4), 256, 0, stream>>>(Wh, Wl, Whp, Wk, Whb, Wlb, Whpb, Wkb);
  cvt_x2<<<dim3(8192, 2), 256, 0, stream>>>(hprev, kin, hprevb, kb16);
  pack_bias<<<10, 256, 0, stream>>>(bw, bt, br, bh, bl, bhp, bk, bias0, bias1, bias2, biasD);

  const int grid = (NROWS / 256) * ((GATES * HDIM) / 128);   // 64*20 = 1280
  // h0 = tanh(xcat W0^T + b0)            K=416 (13 tiles)
  gemm_big<0><<<grid, 512, 0, stream>>>(xcat, nullptr, Wcat, nullptr, bias0, nullptr, bufA, 0, 13, KPAD);
  // h1 = tanh(h0 Whid^T + bhid)          K=512
  gemm_big<0><<<grid, 512, 0, stream>>>(bufA, nullptr, Whb, nullptr, bias1, nullptr, bufB, 1, 16, HDIM);
  // m = tanh(h1 Wlast^T + blast)         K=512
  gemm_big<0><<<grid, 512, 0, stream>>>(bufB, nullptr, Wlb, nullptr, bias2, nullptr, bufA, 1, 16, HDIM);
  // gates = act(hprev Whp^T + k Wk^T + biasD + m)    K=1024
  gemm_big<1><<<grid, 512, 0, stream>>>(hprevb, kb16, Whpb, Wkb, biasD, bufA, bufB, 0, 32, HDIM);
  // c = i*u + f_down*q + f_left*c_prev ; h = o*tanh(c)
  combine<<<4096, 256, 0, stream>>>(bufB, qin, cprev, (float*)d_out);
}

// Round 15
// 391.610 us; speedup vs baseline: 2.0016x; 1.0233x over previous
//
#include <hip/hip_runtime.h>
#include <math.h>

#define NROWS 16384
#define GATES 5
#define HDIM 512
#define KPAD 416   // stage-1 K: 400 real cols padded to 13*32

using bf16x8 = __attribute__((ext_vector_type(8))) short;
using f32x4  = __attribute__((ext_vector_type(4))) float;

__device__ inline float b2f(unsigned short s) {
  unsigned int u = ((unsigned int)s) << 16;
  return __builtin_bit_cast(float, u);
}
__device__ inline unsigned short f2b(float f) {
  unsigned int u = __builtin_bit_cast(unsigned int, f);
  u += 0x7fffu + ((u >> 16) & 1u);   // RNE
  return (unsigned short)(u >> 16);
}

__device__ inline float fast_sigmoid(float x) {
  float t = __builtin_amdgcn_exp2f(-1.4426950408889634f * x);
  return __builtin_amdgcn_rcpf(1.0f + t);
}
__device__ inline float fast_tanh(float x) {
  float t = __builtin_amdgcn_exp2f(2.8853900817779268f * x);
  return 1.0f - 2.0f * __builtin_amdgcn_rcpf(1.0f + t);
}

__device__ inline void gload_lds16(const unsigned short* g, unsigned short* l) {
  __builtin_amdgcn_global_load_lds(
      (const __attribute__((address_space(1))) unsigned int*)(g),
      (__attribute__((address_space(3))) unsigned int*)(l), 16, 0, 0);
}

// ---------------- packing / conversion kernels (f32 -> bf16) ----------------

__global__ void pack_x(const float* __restrict__ word,
                       const float* __restrict__ tag,
                       const float* __restrict__ rel,
                       unsigned short* __restrict__ xcat) {
  int idx = blockIdx.x * 256 + threadIdx.x;       // N*KPAD
  if (idx >= NROWS * KPAD) return;
  int n = idx / KPAD, c = idx % KPAD;
  float v = 0.f;
  if (c < 300)      v = word[n * 300 + c];
  else if (c < 350) v = tag[n * 50 + (c - 300)];
  else if (c < 400) v = rel[n * 50 + (c - 350)];
  xcat[idx] = f2b(v);
}

__global__ void pack_w(const float* __restrict__ Ww,
                       const float* __restrict__ Wt,
                       const float* __restrict__ Wr,
                       unsigned short* __restrict__ Wcat) {
  int idx = blockIdx.x * 256 + threadIdx.x;       // 2560*KPAD
  if (idx >= GATES * HDIM * KPAD) return;
  int gh = idx / KPAD;
  int c = idx % KPAD;
  float v = 0.f;
  if (c < 300)      v = Ww[gh * 300 + c];
  else if (c < 350) v = Wt[gh * 50 + (c - 300)];
  else if (c < 400) v = Wr[gh * 50 + (c - 350)];
  Wcat[idx] = f2b(v);
}

__global__ void cvt_w4(const float* __restrict__ a, const float* __restrict__ b,
                       const float* __restrict__ c, const float* __restrict__ d,
                       unsigned short* oa, unsigned short* ob,
                       unsigned short* oc, unsigned short* od) {
  const float* in; unsigned short* out;
  switch (blockIdx.y) {
    case 0: in = a; out = oa; break;
    case 1: in = b; out = ob; break;
    case 2: in = c; out = oc; break;
    default: in = d; out = od; break;
  }
  int i = (blockIdx.x * 256 + threadIdx.x) * 4;   // 1310720 elems
  float4 v = *(const float4*)(in + i);
  ushort4 o;
  o.x = f2b(v.x); o.y = f2b(v.y); o.z = f2b(v.z); o.w = f2b(v.w);
  *(ushort4*)(out + i) = o;
}

__global__ void cvt_x2(const float* __restrict__ a, const float* __restrict__ b,
                       unsigned short* oa, unsigned short* ob) {
  const float* in = blockIdx.y ? b : a;
  unsigned short* out = blockIdx.y ? ob : oa;
  int i = (blockIdx.x * 256 + threadIdx.x) * 4;   // 8388608 elems
  float4 v = *(const float4*)(in + i);
  ushort4 o;
  o.x = f2b(v.x); o.y = f2b(v.y); o.z = f2b(v.z); o.w = f2b(v.w);
  *(ushort4*)(out + i) = o;
}

__global__ void pack_bias(const float* __restrict__ bw, const float* __restrict__ bt,
                          const float* __restrict__ br, const float* __restrict__ bh,
                          const float* __restrict__ bl, const float* __restrict__ bhp,
                          const float* __restrict__ bk,
                          float* bias0, float* bias1, float* bias2, float* biasD) {
  int i = blockIdx.x * 256 + threadIdx.x;
  if (i < GATES * HDIM) {
    bias0[i] = bw[i] + bt[i] + br[i];
    bias1[i] = bh[i];
    bias2[i] = bl[i];
    biasD[i] = bhp[i] + bk[i];
  }
}

// ---------------- GEMM: 256x128 tile, BK=32, 8 waves ------------------------
// Round 15: (a) swizzle reverted to round-7 form q^((r>>1)&3) — round 9's
// q^(r&3) left even-fr lanes on 2 of 4 slots -> 4-way conflicts (1.3e7 cyc);
// the (r>>1) variant measured ZERO conflicts in round 7. (b) 3-buffer ring,
// stage s+2 ahead, steady vmcnt(6): prefetch gets ~2 tiles of MFMA cover.
// Grid 1280 = 8 XCDs x 160, col-fastest (round 14 verified).
// Epilogue: LDS-staged coalesced writes, static indices (round 12 verified).
// MODE 0: Out = tanh(A*W^T + bias); MODE 1: + A2*W2^T + Madd, gate activation.

template<int MODE>
__global__ __launch_bounds__(512, 2) void gemm_big(
    const unsigned short* __restrict__ A1, const unsigned short* __restrict__ A2,
    const unsigned short* __restrict__ W1, const unsigned short* __restrict__ W2,
    const float* __restrict__ bias,
    const unsigned short* __restrict__ Madd,
    unsigned short* __restrict__ Out,
    int aPerGate, int S, int ld)
{
  __shared__ __align__(16) unsigned short smem[36864];   // 72 KB, aliased
  unsigned short* Ab0 = smem;            // staging A [3][8192]
  unsigned short* Bb0 = smem + 24576;    // staging B [3][4096]
  unsigned short* eps = smem;            // epilogue [64][132]

  // XCD swizzle: 1280 blocks, 8 XCDs, 160 per chunk; col fastest within chunk
  const int bid = (int)blockIdx.x;
  const int swz = (bid & 7) * 160 + (bid >> 3);
  const int col = swz % 20, rowt = swz / 20;
  const int row0  = rowt * 256;
  const int gcol0 = col * 128;                 // [0,2560)
  const int g = gcol0 >> 9;
  const size_t aslab = aPerGate ? (size_t)g * NROWS * ld : 0;

  const int t = threadIdx.x;
  const int wid = t >> 6, l = t & 63;
  const int wrow = (wid >> 2) * 128;           // 2 M-groups
  const int wcol = (wid & 3) * 32;             // 4 N-groups x 32 cols
  const int fr = l & 15, q = l >> 4;

  f32x4 acc[8][2];
#pragma unroll
  for (int mi = 0; mi < 8; ++mi)
#pragma unroll
    for (int ni = 0; ni < 2; ++ni)
      acc[mi][ni] = (f32x4){0.f, 0.f, 0.f, 0.f};

  // staging: A 2 issues (rows j*128+(t>>2)), B 1 issue (rows t>>2); dst linear.
  // LDS[row][phys] holds global slot phys^((row>>1)&3)  (involution both sides)
  auto stage = [&](int c, int buf) {
    const unsigned short* Asrc; const unsigned short* Wsrc; int kloc;
    if (MODE == 1 && c >= 16) { Asrc = A2;         Wsrc = W2; kloc = (c - 16) * 32; }
    else                      { Asrc = A1 + aslab; Wsrc = W1; kloc = c * 32; }
    const int rb = t >> 2;
#pragma unroll
    for (int j = 0; j < 2; ++j) {
      const int r = j * 128 + rb;
      const int sgj = ((t & 3) ^ ((r >> 1) & 3)) * 8;
      gload_lds16(Asrc + (size_t)(row0 + r) * ld + kloc + sgj, &Ab0[buf * 8192 + j * 4096 + t * 8]);
    }
    const int sg = ((t & 3) ^ ((rb >> 1) & 3)) * 8;
    gload_lds16(Wsrc + (size_t)(gcol0 + rb) * ld + kloc + sg, &Bb0[buf * 4096 + t * 8]);
  };

  stage(0, 0);
  if (S > 1) stage(1, 1);

  for (int s = 0; s < S; ++s) {
    const int buf = s % 3;
    if (s + 2 < S) {
      stage(s + 2, (s + 2) % 3);   // 2 tiles in flight over this tile's compute
      asm volatile("s_waitcnt vmcnt(6)" ::: "memory");   // tile-s landed only
    } else if (s + 1 < S) {
      asm volatile("s_waitcnt vmcnt(3)" ::: "memory");
    } else {
      asm volatile("s_waitcnt vmcnt(0)" ::: "memory");
    }
    __builtin_amdgcn_s_barrier();

    bf16x8 bq[2];
#pragma unroll
    for (int ni = 0; ni < 2; ++ni) {
      const int r = wcol + ni * 16 + fr;
      bq[ni] = *reinterpret_cast<const bf16x8*>(&Bb0[buf * 4096 + r * 32 + ((q ^ ((r >> 1) & 3)) * 8)]);
    }
#pragma unroll
    for (int p = 0; p < 2; ++p) {
      bf16x8 af[4];
#pragma unroll
      for (int mi = 0; mi < 4; ++mi) {
        const int r = wrow + (p * 4 + mi) * 16 + fr;
        af[mi] = *reinterpret_cast<const bf16x8*>(&Ab0[buf * 8192 + r * 32 + ((q ^ ((r >> 1) & 3)) * 8)]);
      }
      __builtin_amdgcn_s_setprio(1);
#pragma unroll
      for (int mi = 0; mi < 4; ++mi)
#pragma unroll
        for (int ni = 0; ni < 2; ++ni)
          acc[p * 4 + mi][ni] = __builtin_amdgcn_mfma_f32_16x16x32_bf16(af[mi], bq[ni], acc[p * 4 + mi][ni], 0, 0, 0);
      __builtin_amdgcn_s_setprio(0);
    }
    __builtin_amdgcn_s_barrier();   // reads of buf done -> restage of buf safe
  }

  // ---- coalesced epilogue: 4 passes of 64 rows x 128 cols through LDS -------
  const size_t NM = (size_t)NROWS * HDIM;
  unsigned short* outg = Out + (size_t)g * NM;
  const int colbase = gcol0 & 511;
  float bv[2];
#pragma unroll
  for (int ni = 0; ni < 2; ++ni)
    bv[ni] = bias[g * HDIM + colbase + wcol + ni * 16 + fr];

#pragma unroll
  for (int h = 0; h < 4; ++h) {
    __builtin_amdgcn_s_barrier();          // prior read-pass done
    if ((wid >> 2) == (h >> 1)) {          // owning wave-group writes
      const int mib = (h & 1) * 4;         // compile-time after unroll
#pragma unroll
      for (int mi2 = 0; mi2 < 4; ++mi2)
#pragma unroll
        for (int ni = 0; ni < 2; ++ni)
#pragma unroll
          for (int j = 0; j < 4; ++j)
            eps[(mi2 * 16 + q * 4 + j) * 132 + wcol + ni * 16 + fr] =
                f2b(acc[mib + mi2][ni][j] + bv[ni]);
    }
    __builtin_amdgcn_s_barrier();
#pragma unroll
    for (int v = 0; v < 2; ++v) {
      const int c  = v * 512 + t;          // 1024 chunks of 16B
      const int rl = c >> 4;               // 0..63
      const int cc = (c & 15) * 8;         // shorts, 0..120
      const int gr = row0 + h * 64 + rl;
      bf16x8 pv = *reinterpret_cast<const bf16x8*>(&eps[rl * 132 + cc]);
      bf16x8 ov;
      if (MODE == 1) {
        bf16x8 mv = *reinterpret_cast<const bf16x8*>(
            Madd + (size_t)g * NM + (size_t)gr * HDIM + colbase + cc);
#pragma unroll
        for (int e = 0; e < 8; ++e) {
          float f = b2f((unsigned short)pv[e]) + b2f((unsigned short)mv[e]);
          f = (g < 4) ? fast_sigmoid(f) : fast_tanh(f);
          ov[e] = (short)f2b(f);
        }
      } else {
#pragma unroll
        for (int e = 0; e < 8; ++e)
          ov[e] = (short)f2b(fast_tanh(b2f((unsigned short)pv[e])));
      }
      *reinterpret_cast<bf16x8*>(&outg[(size_t)gr * HDIM + colbase + cc]) = ov;
    }
  }
}

// ---------------- final elementwise combine (f32 q/c_prev, f32 out) ---------

__device__ inline float exb(const uint4& v, int j) {
  unsigned int wd = ((const unsigned int*)&v)[j >> 1];
  return b2f((unsigned short)(wd >> ((j & 1) * 16)));
}

__global__ void combine(const unsigned short* __restrict__ gates,
                        const float* __restrict__ q,
                        const float* __restrict__ cp,
                        float* __restrict__ out) {
  const size_t NM = (size_t)NROWS * HDIM;
  size_t i8 = ((size_t)blockIdx.x * 256 + threadIdx.x) * 8;
  if (i8 >= NM) return;
  uint4 gi = *(const uint4*)(gates + 0 * NM + i8);
  uint4 gf = *(const uint4*)(gates + 1 * NM + i8);
  uint4 gl = *(const uint4*)(gates + 2 * NM + i8);
  uint4 go = *(const uint4*)(gates + 3 * NM + i8);
  uint4 gu = *(const uint4*)(gates + 4 * NM + i8);
  float4 q0 = *(const float4*)(q + i8);
  float4 q1 = *(const float4*)(q + i8 + 4);
  float4 p0 = *(const float4*)(cp + i8);
  float4 p1 = *(const float4*)(cp + i8 + 4);
  float qv[8] = {q0.x, q0.y, q0.z, q0.w, q1.x, q1.y, q1.z, q1.w};
  float pv[8] = {p0.x, p0.y, p0.z, p0.w, p1.x, p1.y, p1.z, p1.w};
  float hv[8], cv[8];
#pragma unroll
  for (int j = 0; j < 8; ++j) {
    float c = exb(gi, j) * exb(gu, j) + exb(gf, j) * qv[j] + exb(gl, j) * pv[j];
    hv[j] = exb(go, j) * fast_tanh(c);
    cv[j] = c;
  }
  *(float4*)(out + i8)      = make_float4(hv[0], hv[1], hv[2], hv[3]);
  *(float4*)(out + i8 + 4)  = make_float4(hv[4], hv[5], hv[6], hv[7]);
  *(float4*)(out + NM + i8)     = make_float4(cv[0], cv[1], cv[2], cv[3]);
  *(float4*)(out + NM + i8 + 4) = make_float4(cv[4], cv[5], cv[6], cv[7]);
}

// ---------------- launch ----------------

extern "C" void kernel_launch(void* const* d_in, const int* in_sizes, int n_in,
                              void* d_out, int out_size, void* d_ws, size_t ws_size,
                              hipStream_t stream) {
  const float* word  = (const float*)d_in[0];
  const float* tag   = (const float*)d_in[1];
  const float* rel   = (const float*)d_in[2];
  const float* kin   = (const float*)d_in[3];
  const float* qin   = (const float*)d_in[4];
  const float* hprev = (const float*)d_in[5];
  const float* cprev = (const float*)d_in[6];
  const float* Ww    = (const float*)d_in[7];
  const float* bw    = (const float*)d_in[8];
  const float* Wt    = (const float*)d_in[9];
  const float* bt    = (const float*)d_in[10];
  const float* Wr    = (const float*)d_in[11];
  const float* br    = (const float*)d_in[12];
  const float* Wh    = (const float*)d_in[13];
  const float* bh    = (const float*)d_in[14];
  const float* Wl    = (const float*)d_in[15];
  const float* bl    = (const float*)d_in[16];
  const float* Whp   = (const float*)d_in[17];
  const float* bhp   = (const float*)d_in[18];
  const float* Wk    = (const float*)d_in[19];
  const float* bk    = (const float*)d_in[20];

  char* ws = (char*)d_ws;
  unsigned short* xcat   = (unsigned short*)(ws);                 // 13,631,488 B
  unsigned short* Wcat   = (unsigned short*)(ws + 13631488);      //  2,129,920 B
  unsigned short* Whb    = (unsigned short*)(ws + 15761408);      //  2,621,440 B
  unsigned short* Wlb    = (unsigned short*)(ws + 18382848);
  unsigned short* Whpb   = (unsigned short*)(ws + 21004288);
  unsigned short* Wkb    = (unsigned short*)(ws + 23625728);
  unsigned short* hprevb = (unsigned short*)(ws + 26247168);      // 16,777,216 B
  unsigned short* kb16   = (unsigned short*)(ws + 43024384);      // 16,777,216 B
  float* bias0           = (float*)(ws + 59801600);
  float* bias1           = (float*)(ws + 59811840);
  float* bias2           = (float*)(ws + 59822080);
  float* biasD           = (float*)(ws + 59832320);
  unsigned short* bufA   = (unsigned short*)(ws + 59842560);      // 83,886,080 B
  unsigned short* bufB   = (unsigned short*)(ws + 143728640);     // 83,886,080 B
  // total: 227,614,720 B

  pack_x<<<26624, 256, 0, stream>>>(word, tag, rel, xcat);
  pack_w<<<4160, 256, 0, stream>>>(Ww, Wt, Wr, Wcat);
  cvt_w4<<<dim3(1280, 4), 256, 0, stream>>>(Wh, Wl, Whp, Wk, Whb, Wlb, Whpb, Wkb);
  cvt_x2<<<dim3(8192, 2), 256, 0, stream>>>(hprev, kin, hprevb, kb16);
  pack_bias<<<10, 256, 0, stream>>>(bw, bt, br, bh, bl, bhp, bk, bias0, bias1, bias2, biasD);

  const int grid = (NROWS / 256) * ((GATES * HDIM) / 128);   // 64*20 = 1280
  // h0 = tanh(xcat W0^T + b0)            K=416 (13 tiles)
  gemm_big<0><<<grid, 512, 0, stream>>>(xcat, nullptr, Wcat, nullptr, bias0, nullptr, bufA, 0, 13, KPAD);
  // h1 = tanh(h0 Whid^T + bhid)          K=512
  gemm_big<0><<<grid, 512, 0, stream>>>(bufA, nullptr, Whb, nullptr, bias1, nullptr, bufB, 1, 16, HDIM);
  // m = tanh(h1 Wlast^T + blast)         K=512
  gemm_big<0><<<grid, 512, 0, stream>>>(bufB, nullptr, Wlb, nullptr, bias2, nullptr, bufA, 1, 16, HDIM);
  // gates = act(hprev Whp^T + k Wk^T + biasD + m)    K=1024
  gemm_big<1><<<grid, 512, 0, stream>>>(hprevb, kb16, Whpb, Wkb, biasD, bufA, bufB, 0, 32, HDIM);
  // c = i*u + f_down*q + f_left*c_prev ; h = o*tanh(c)
  combine<<<4096, 256, 0, stream>>>(bufB, qin, cprev, (float*)d_out);
}

// Round 17
// 358.735 us; speedup vs baseline: 2.1851x; 1.0916x over previous
//
#include <hip/hip_runtime.h>
#include <math.h>

#define NROWS 16384
#define GATES 5
#define HDIM 512
#define KPAD 416   // stage-1 K: 400 real cols padded to 13*32

using bf16x8 = __attribute__((ext_vector_type(8))) short;
using f32x4  = __attribute__((ext_vector_type(4))) float;

__device__ inline float b2f(unsigned short s) {
  unsigned int u = ((unsigned int)s) << 16;
  return __builtin_bit_cast(float, u);
}
__device__ inline unsigned short f2b(float f) {
  unsigned int u = __builtin_bit_cast(unsigned int, f);
  u += 0x7fffu + ((u >> 16) & 1u);   // RNE
  return (unsigned short)(u >> 16);
}

__device__ inline float fast_sigmoid(float x) {
  float t = __builtin_amdgcn_exp2f(-1.4426950408889634f * x);
  return __builtin_amdgcn_rcpf(1.0f + t);
}
__device__ inline float fast_tanh(float x) {
  float t = __builtin_amdgcn_exp2f(2.8853900817779268f * x);
  return 1.0f - 2.0f * __builtin_amdgcn_rcpf(1.0f + t);
}

__device__ inline void gload_lds16(const unsigned short* g, unsigned short* l) {
  __builtin_amdgcn_global_load_lds(
      (const __attribute__((address_space(1))) unsigned int*)(g),
      (__attribute__((address_space(3))) unsigned int*)(l), 16, 0, 0);
}

// compiler memory fence (zero instructions): s_barrier is IntrNoMem to LLVM,
// so memory ops/intrinsics CAN cross it unless pinned. Bracket every barrier.
__device__ inline void cfence() { asm volatile("" ::: "memory"); }
__device__ inline void hard_barrier() {
  cfence();
  __builtin_amdgcn_s_barrier();
  cfence();
}

// ---------------- packing / conversion kernels (f32 -> bf16) ----------------

__global__ void pack_x(const float* __restrict__ word,
                       const float* __restrict__ tag,
                       const float* __restrict__ rel,
                       unsigned short* __restrict__ xcat) {
  int idx = blockIdx.x * 256 + threadIdx.x;       // N*KPAD
  if (idx >= NROWS * KPAD) return;
  int n = idx / KPAD, c = idx % KPAD;
  float v = 0.f;
  if (c < 300)      v = word[n * 300 + c];
  else if (c < 350) v = tag[n * 50 + (c - 300)];
  else if (c < 400) v = rel[n * 50 + (c - 350)];
  xcat[idx] = f2b(v);
}

__global__ void pack_w(const float* __restrict__ Ww,
                       const float* __restrict__ Wt,
                       const float* __restrict__ Wr,
                       unsigned short* __restrict__ Wcat) {
  int idx = blockIdx.x * 256 + threadIdx.x;       // 2560*KPAD
  if (idx >= GATES * HDIM * KPAD) return;
  int gh = idx / KPAD;
  int c = idx % KPAD;
  float v = 0.f;
  if (c < 300)      v = Ww[gh * 300 + c];
  else if (c < 350) v = Wt[gh * 50 + (c - 300)];
  else if (c < 400) v = Wr[gh * 50 + (c - 350)];
  Wcat[idx] = f2b(v);
}

__global__ void cvt_w4(const float* __restrict__ a, const float* __restrict__ b,
                       const float* __restrict__ c, const float* __restrict__ d,
                       unsigned short* oa, unsigned short* ob,
                       unsigned short* oc, unsigned short* od) {
  const float* in; unsigned short* out;
  switch (blockIdx.y) {
    case 0: in = a; out = oa; break;
    case 1: in = b; out = ob; break;
    case 2: in = c; out = oc; break;
    default: in = d; out = od; break;
  }
  int i = (blockIdx.x * 256 + threadIdx.x) * 4;   // 1310720 elems
  float4 v = *(const float4*)(in + i);
  ushort4 o;
  o.x = f2b(v.x); o.y = f2b(v.y); o.z = f2b(v.z); o.w = f2b(v.w);
  *(ushort4*)(out + i) = o;
}

__global__ void cvt_x2(const float* __restrict__ a, const float* __restrict__ b,
                       unsigned short* oa, unsigned short* ob) {
  const float* in = blockIdx.y ? b : a;
  unsigned short* out = blockIdx.y ? ob : oa;
  int i = (blockIdx.x * 256 + threadIdx.x) * 4;   // 8388608 elems
  float4 v = *(const float4*)(in + i);
  ushort4 o;
  o.x = f2b(v.x); o.y = f2b(v.y); o.z = f2b(v.z); o.w = f2b(v.w);
  *(ushort4*)(out + i) = o;
}

__global__ void pack_bias(const float* __restrict__ bw, const float* __restrict__ bt,
                          const float* __restrict__ br, const float* __restrict__ bh,
                          const float* __restrict__ bl, const float* __restrict__ bhp,
                          const float* __restrict__ bk,
                          float* bias0, float* bias1, float* bias2, float* biasD) {
  int i = blockIdx.x * 256 + threadIdx.x;
  if (i < GATES * HDIM) {
    bias0[i] = bw[i] + bt[i] + br[i];
    bias1[i] = bh[i];
    bias2[i] = bl[i];
    biasD[i] = bhp[i] + bk[i];
  }
}

// ---------------- shared GEMM machinery (round 15 ring, hardened) ------------
// 256x128 tile, BK=32, 8 waves, 3-buf ring, counted vmcnt, zero-conflict
// swizzle q^((r>>1)&3), XCD-aware grid 1280 = 8 x 160 col-fastest,
// LDS-staged coalesced epilogue. All barriers compiler-fenced (round-16 race:
// stage hoisted above a raw s_barrier corrupted a buffer other waves read).

// ---------------- stages 1-2: Out = tanh(A*W^T + bias) ----------------------

__global__ __launch_bounds__(512, 2) void gemm_mlp(
    const unsigned short* __restrict__ A1,
    const unsigned short* __restrict__ W1,
    const float* __restrict__ bias,
    unsigned short* __restrict__ Out,
    int aPerGate, int S, int ld)
{
  __shared__ __align__(16) unsigned short smem[36864];   // 72 KB, aliased
  unsigned short* Ab0 = smem;            // staging A [3][8192]
  unsigned short* Bb0 = smem + 24576;    // staging B [3][4096]
  unsigned short* eps = smem;            // epilogue [64][132]

  const int bid = (int)blockIdx.x;
  const int swz = (bid & 7) * 160 + (bid >> 3);
  const int col = swz % 20, rowt = swz / 20;
  const int row0  = rowt * 256;
  const int gcol0 = col * 128;                 // [0,2560)
  const int g = gcol0 >> 9;
  const size_t aslab = aPerGate ? (size_t)g * NROWS * ld : 0;

  const int t = threadIdx.x;
  const int wid = t >> 6, l = t & 63;
  const int wrow = (wid >> 2) * 128;
  const int wcol = (wid & 3) * 32;
  const int fr = l & 15, q = l >> 4;

  f32x4 acc[8][2];
#pragma unroll
  for (int mi = 0; mi < 8; ++mi)
#pragma unroll
    for (int ni = 0; ni < 2; ++ni)
      acc[mi][ni] = (f32x4){0.f, 0.f, 0.f, 0.f};

  auto stage = [&](int c, int buf) {
    const int kloc = c * 32;
    const int rb = t >> 2;
#pragma unroll
    for (int j = 0; j < 2; ++j) {
      const int r = j * 128 + rb;
      const int sgj = ((t & 3) ^ ((r >> 1) & 3)) * 8;
      gload_lds16(A1 + aslab + (size_t)(row0 + r) * ld + kloc + sgj, &Ab0[buf * 8192 + j * 4096 + t * 8]);
    }
    const int sg = ((t & 3) ^ ((rb >> 1) & 3)) * 8;
    gload_lds16(W1 + (size_t)(gcol0 + rb) * ld + kloc + sg, &Bb0[buf * 4096 + t * 8]);
  };

  cfence();
  stage(0, 0);
  if (S > 1) stage(1, 1);
  cfence();

  for (int s = 0; s < S; ++s) {
    const int buf = s % 3;
    if (s + 2 < S) {
      stage(s + 2, (s + 2) % 3);
      asm volatile("s_waitcnt vmcnt(6)" ::: "memory");
    } else if (s + 1 < S) {
      asm volatile("s_waitcnt vmcnt(3)" ::: "memory");
    } else {
      asm volatile("s_waitcnt vmcnt(0)" ::: "memory");
    }
    hard_barrier();

    bf16x8 bq[2];
#pragma unroll
    for (int ni = 0; ni < 2; ++ni) {
      const int r = wcol + ni * 16 + fr;
      bq[ni] = *reinterpret_cast<const bf16x8*>(&Bb0[buf * 4096 + r * 32 + ((q ^ ((r >> 1) & 3)) * 8)]);
    }
#pragma unroll
    for (int p = 0; p < 2; ++p) {
      bf16x8 af[4];
#pragma unroll
      for (int mi = 0; mi < 4; ++mi) {
        const int r = wrow + (p * 4 + mi) * 16 + fr;
        af[mi] = *reinterpret_cast<const bf16x8*>(&Ab0[buf * 8192 + r * 32 + ((q ^ ((r >> 1) & 3)) * 8)]);
      }
      __builtin_amdgcn_s_setprio(1);
#pragma unroll
      for (int mi = 0; mi < 4; ++mi)
#pragma unroll
        for (int ni = 0; ni < 2; ++ni)
          acc[p * 4 + mi][ni] = __builtin_amdgcn_mfma_f32_16x16x32_bf16(af[mi], bq[ni], acc[p * 4 + mi][ni], 0, 0, 0);
      __builtin_amdgcn_s_setprio(0);
    }
    hard_barrier();   // reads of buf done -> restage of buf safe
  }

  // coalesced epilogue
  const size_t NM = (size_t)NROWS * HDIM;
  unsigned short* outg = Out + (size_t)g * NM;
  const int colbase = gcol0 & 511;
  float bv[2];
#pragma unroll
  for (int ni = 0; ni < 2; ++ni)
    bv[ni] = bias[g * HDIM + colbase + wcol + ni * 16 + fr];

#pragma unroll
  for (int h = 0; h < 4; ++h) {
    hard_barrier();                        // prior read-pass done
    if ((wid >> 2) == (h >> 1)) {
      const int mib = (h & 1) * 4;
#pragma unroll
      for (int mi2 = 0; mi2 < 4; ++mi2)
#pragma unroll
        for (int ni = 0; ni < 2; ++ni)
#pragma unroll
          for (int j = 0; j < 4; ++j)
            eps[(mi2 * 16 + q * 4 + j) * 132 + wcol + ni * 16 + fr] =
                f2b(fast_tanh(acc[mib + mi2][ni][j] + bv[ni]));
    }
    asm volatile("s_waitcnt lgkmcnt(0)" ::: "memory");   // publish eps writes
    hard_barrier();
#pragma unroll
    for (int v = 0; v < 2; ++v) {
      const int c  = v * 512 + t;
      const int rl = c >> 4;
      const int cc = (c & 15) * 8;
      const int gr = row0 + h * 64 + rl;
      bf16x8 pv = *reinterpret_cast<const bf16x8*>(&eps[rl * 132 + cc]);
      *reinterpret_cast<bf16x8*>(&outg[(size_t)gr * HDIM + colbase + cc]) = pv;
    }
  }
}

// ---------------- fused stages C+D: gates = act(tanh(h1 Wl^T + b2) + bD
//                                               + hprev Whp^T + k Wk^T) -------
// Accumulator-chained fusion: GEMM1 -> acc = tanh(acc+b2)+bD (in place) ->
// GEMM2 accumulates on top -> gate activation. Kills the m buffer (84 MB
// write + 84 MB read) and one dispatch.

__global__ __launch_bounds__(512, 2) void gemm_cd(
    const unsigned short* __restrict__ H1,    // [G][N][512]
    const unsigned short* __restrict__ Hp,    // [N][512]
    const unsigned short* __restrict__ Kb,    // [N][512]
    const unsigned short* __restrict__ Wl,    // [2560][512]
    const unsigned short* __restrict__ Whp,   // [2560][512]
    const unsigned short* __restrict__ Wk,    // [2560][512]
    const float* __restrict__ bias2, const float* __restrict__ biasD,
    unsigned short* __restrict__ Out)         // gates [G][N][512]
{
  __shared__ __align__(16) unsigned short smem[36864];
  unsigned short* Ab0 = smem;
  unsigned short* Bb0 = smem + 24576;
  unsigned short* eps = smem;

  const int bid = (int)blockIdx.x;
  const int swz = (bid & 7) * 160 + (bid >> 3);
  const int col = swz % 20, rowt = swz / 20;
  const int row0  = rowt * 256;
  const int gcol0 = col * 128;
  const int g = gcol0 >> 9;

  const int t = threadIdx.x;
  const int wid = t >> 6, l = t & 63;
  const int wrow = (wid >> 2) * 128;
  const int wcol = (wid & 3) * 32;
  const int fr = l & 15, q = l >> 4;

  f32x4 acc[8][2];
#pragma unroll
  for (int mi = 0; mi < 8; ++mi)
#pragma unroll
    for (int ni = 0; ni < 2; ++ni)
      acc[mi][ni] = (f32x4){0.f, 0.f, 0.f, 0.f};

  auto stageG = [&](const unsigned short* Asrc, const unsigned short* Wsrc,
                    int kloc, int buf) {
    const int rb = t >> 2;
#pragma unroll
    for (int j = 0; j < 2; ++j) {
      const int r = j * 128 + rb;
      const int sgj = ((t & 3) ^ ((r >> 1) & 3)) * 8;
      gload_lds16(Asrc + (size_t)(row0 + r) * HDIM + kloc + sgj, &Ab0[buf * 8192 + j * 4096 + t * 8]);
    }
    const int sg = ((t & 3) ^ ((rb >> 1) & 3)) * 8;
    gload_lds16(Wsrc + (size_t)(gcol0 + rb) * HDIM + kloc + sg, &Bb0[buf * 4096 + t * 8]);
  };

  auto runloop = [&](int S, auto srcpick) {
    cfence();
    { auto s0 = srcpick(0); stageG(s0.a, s0.w, s0.k, 0); }
    if (S > 1) { auto s1 = srcpick(1); stageG(s1.a, s1.w, s1.k, 1); }
    cfence();
    for (int s = 0; s < S; ++s) {
      const int buf = s % 3;
      if (s + 2 < S) {
        auto sn = srcpick(s + 2);
        stageG(sn.a, sn.w, sn.k, (s + 2) % 3);
        asm volatile("s_waitcnt vmcnt(6)" ::: "memory");
      } else if (s + 1 < S) {
        asm volatile("s_waitcnt vmcnt(3)" ::: "memory");
      } else {
        asm volatile("s_waitcnt vmcnt(0)" ::: "memory");
      }
      hard_barrier();

      bf16x8 bq[2];
#pragma unroll
      for (int ni = 0; ni < 2; ++ni) {
        const int r = wcol + ni * 16 + fr;
        bq[ni] = *reinterpret_cast<const bf16x8*>(&Bb0[buf * 4096 + r * 32 + ((q ^ ((r >> 1) & 3)) * 8)]);
      }
#pragma unroll
      for (int p = 0; p < 2; ++p) {
        bf16x8 af[4];
#pragma unroll
        for (int mi = 0; mi < 4; ++mi) {
          const int r = wrow + (p * 4 + mi) * 16 + fr;
          af[mi] = *reinterpret_cast<const bf16x8*>(&Ab0[buf * 8192 + r * 32 + ((q ^ ((r >> 1) & 3)) * 8)]);
        }
        __builtin_amdgcn_s_setprio(1);
#pragma unroll
        for (int mi = 0; mi < 4; ++mi)
#pragma unroll
          for (int ni = 0; ni < 2; ++ni)
            acc[p * 4 + mi][ni] = __builtin_amdgcn_mfma_f32_16x16x32_bf16(af[mi], bq[ni], acc[p * 4 + mi][ni], 0, 0, 0);
        __builtin_amdgcn_s_setprio(0);
      }
      hard_barrier();   // reads of buf done -> restage of buf safe
    }
  };

  struct Src { const unsigned short* a; const unsigned short* w; int k; };
  const size_t NM = (size_t)NROWS * HDIM;

  // GEMM1: acc = h1[g] * Wl[g]^T   (K=512)
  const unsigned short* h1g = H1 + (size_t)g * NM;
  runloop(16, [&](int c) -> Src { return {h1g, Wl, c * 32}; });

  // in-place accumulator transform: acc = tanh(acc + bias2) + biasD
  const int colbase = gcol0 & 511;
#pragma unroll
  for (int ni = 0; ni < 2; ++ni) {
    const float b2 = bias2[g * HDIM + colbase + wcol + ni * 16 + fr];
    const float bD = biasD[g * HDIM + colbase + wcol + ni * 16 + fr];
#pragma unroll
    for (int mi = 0; mi < 8; ++mi)
#pragma unroll
      for (int j = 0; j < 4; ++j)
        acc[mi][ni][j] = fast_tanh(acc[mi][ni][j] + b2) + bD;
  }

  // GEMM2: acc += hprev * Whp[g]^T + k * Wk[g]^T   (K=1024)
  runloop(32, [&](int c) -> Src {
    return (c < 16) ? Src{Hp, Whp, c * 32} : Src{Kb, Wk, (c - 16) * 32};
  });

  // epilogue: gate activation at LDS-write, coalesced copy out
  unsigned short* outg = Out + (size_t)g * NM;
#pragma unroll
  for (int h = 0; h < 4; ++h) {
    hard_barrier();
    if ((wid >> 2) == (h >> 1)) {
      const int mib = (h & 1) * 4;
#pragma unroll
      for (int mi2 = 0; mi2 < 4; ++mi2)
#pragma unroll
        for (int ni = 0; ni < 2; ++ni)
#pragma unroll
          for (int j = 0; j < 4; ++j) {
            float v = acc[mib + mi2][ni][j];
            v = (g < 4) ? fast_sigmoid(v) : fast_tanh(v);
            eps[(mi2 * 16 + q * 4 + j) * 132 + wcol + ni * 16 + fr] = f2b(v);
          }
    }
    asm volatile("s_waitcnt lgkmcnt(0)" ::: "memory");   // publish eps writes
    hard_barrier();
#pragma unroll
    for (int v = 0; v < 2; ++v) {
      const int c  = v * 512 + t;
      const int rl = c >> 4;
      const int cc = (c & 15) * 8;
      const int gr = row0 + h * 64 + rl;
      bf16x8 pv = *reinterpret_cast<const bf16x8*>(&eps[rl * 132 + cc]);
      *reinterpret_cast<bf16x8*>(&outg[(size_t)gr * HDIM + colbase + cc]) = pv;
    }
  }
}

// ---------------- final elementwise combine (f32 q/c_prev, f32 out) ---------

__device__ inline float exb(const uint4& v, int j) {
  unsigned int wd = ((const unsigned int*)&v)[j >> 1];
  return b2f((unsigned short)(wd >> ((j & 1) * 16)));
}

__global__ void combine(const unsigned short* __restrict__ gates,
                        const float* __restrict__ q,
                        const float* __restrict__ cp,
                        float* __restrict__ out) {
  const size_t NM = (size_t)NROWS * HDIM;
  size_t i8 = ((size_t)blockIdx.x * 256 + threadIdx.x) * 8;
  if (i8 >= NM) return;
  uint4 gi = *(const uint4*)(gates + 0 * NM + i8);
  uint4 gf = *(const uint4*)(gates + 1 * NM + i8);
  uint4 gl = *(const uint4*)(gates + 2 * NM + i8);
  uint4 go = *(const uint4*)(gates + 3 * NM + i8);
  uint4 gu = *(const uint4*)(gates + 4 * NM + i8);
  float4 q0 = *(const float4*)(q + i8);
  float4 q1 = *(const float4*)(q + i8 + 4);
  float4 p0 = *(const float4*)(cp + i8);
  float4 p1 = *(const float4*)(cp + i8 + 4);
  float qv[8] = {q0.x, q0.y, q0.z, q0.w, q1.x, q1.y, q1.z, q1.w};
  float pv[8] = {p0.x, p0.y, p0.z, p0.w, p1.x, p1.y, p1.z, p1.w};
  float hv[8], cv[8];
#pragma unroll
  for (int j = 0; j < 8; ++j) {
    float c = exb(gi, j) * exb(gu, j) + exb(gf, j) * qv[j] + exb(gl, j) * pv[j];
    hv[j] = exb(go, j) * fast_tanh(c);
    cv[j] = c;
  }
  *(float4*)(out + i8)      = make_float4(hv[0], hv[1], hv[2], hv[3]);
  *(float4*)(out + i8 + 4)  = make_float4(hv[4], hv[5], hv[6], hv[7]);
  *(float4*)(out + NM + i8)     = make_float4(cv[0], cv[1], cv[2], cv[3]);
  *(float4*)(out + NM + i8 + 4) = make_float4(cv[4], cv[5], cv[6], cv[7]);
}

// ---------------- launch ----------------

extern "C" void kernel_launch(void* const* d_in, const int* in_sizes, int n_in,
                              void* d_out, int out_size, void* d_ws, size_t ws_size,
                              hipStream_t stream) {
  const float* word  = (const float*)d_in[0];
  const float* tag   = (const float*)d_in[1];
  const float* rel   = (const float*)d_in[2];
  const float* kin   = (const float*)d_in[3];
  const float* qin   = (const float*)d_in[4];
  const float* hprev = (const float*)d_in[5];
  const float* cprev = (const float*)d_in[6];
  const float* Ww    = (const float*)d_in[7];
  const float* bw    = (const float*)d_in[8];
  const float* Wt    = (const float*)d_in[9];
  const float* bt    = (const float*)d_in[10];
  const float* Wr    = (const float*)d_in[11];
  const float* br    = (const float*)d_in[12];
  const float* Wh    = (const float*)d_in[13];
  const float* bh    = (const float*)d_in[14];
  const float* Wl    = (const float*)d_in[15];
  const float* bl    = (const float*)d_in[16];
  const float* Whp   = (const float*)d_in[17];
  const float* bhp   = (const float*)d_in[18];
  const float* Wk    = (const float*)d_in[19];
  const float* bk    = (const float*)d_in[20];

  char* ws = (char*)d_ws;
  unsigned short* xcat   = (unsigned short*)(ws);                 // 13,631,488 B
  unsigned short* Wcat   = (unsigned short*)(ws + 13631488);      //  2,129,920 B
  unsigned short* Whb    = (unsigned short*)(ws + 15761408);      //  2,621,440 B
  unsigned short* Wlb    = (unsigned short*)(ws + 18382848);
  unsigned short* Whpb   = (unsigned short*)(ws + 21004288);
  unsigned short* Wkb    = (unsigned short*)(ws + 23625728);
  unsigned short* hprevb = (unsigned short*)(ws + 26247168);      // 16,777,216 B
  unsigned short* kb16   = (unsigned short*)(ws + 43024384);      // 16,777,216 B
  float* bias0           = (float*)(ws + 59801600);
  float* bias1           = (float*)(ws + 59811840);
  float* bias2           = (float*)(ws + 59822080);
  float* biasD           = (float*)(ws + 59832320);
  unsigned short* bufA   = (unsigned short*)(ws + 59842560);      // 83,886,080 B
  unsigned short* bufB   = (unsigned short*)(ws + 143728640);     // 83,886,080 B
  // total: 227,614,720 B

  pack_x<<<26624, 256, 0, stream>>>(word, tag, rel, xcat);
  pack_w<<<4160, 256, 0, stream>>>(Ww, Wt, Wr, Wcat);
  cvt_w4<<<dim3(1280, 4), 256, 0, stream>>>(Wh, Wl, Whp, Wk, Whb, Wlb, Whpb, Wkb);
  cvt_x2<<<dim3(8192, 2), 256, 0, stream>>>(hprev, kin, hprevb, kb16);
  pack_bias<<<10, 256, 0, stream>>>(bw, bt, br, bh, bl, bhp, bk, bias0, bias1, bias2, biasD);

  const int grid = (NROWS / 256) * ((GATES * HDIM) / 128);   // 64*20 = 1280
  // h0 = tanh(xcat W0^T + b0)            K=416 (13 tiles)
  gemm_mlp<<<grid, 512, 0, stream>>>(xcat, Wcat, bias0, bufA, 0, 13, KPAD);
  // h1 = tanh(h0 Whid^T + bhid)          K=512
  gemm_mlp<<<grid, 512, 0, stream>>>(bufA, Whb, bias1, bufB, 1, 16, HDIM);
  // gates = act(tanh(h1 Wl^T + b2) + bD + hprev Whp^T + k Wk^T)   fused C+D
  gemm_cd<<<grid, 512, 0, stream>>>(bufB, hprevb, kb16, Wlb, Whpb, Wkb,
                                    bias2, biasD, bufA);
  // c = i*u + f_down*q + f_left*c_prev ; h = o*tanh(c)
  combine<<<4096, 256, 0, stream>>>(bufA, qin, cprev, (float*)d_out);
}

// Round 18
// 344.529 us; speedup vs baseline: 2.2752x; 1.0412x over previous
//
#include <hip/hip_runtime.h>
#include <math.h>

#define NROWS 16384
#define GATES 5
#define HDIM 512
#define KPAD 416   // stage-1 K: 400 real cols padded to 13*32

using bf16x8 = __attribute__((ext_vector_type(8))) short;
using f32x4  = __attribute__((ext_vector_type(4))) float;

__device__ inline float b2f(unsigned short s) {
  unsigned int u = ((unsigned int)s) << 16;
  return __builtin_bit_cast(float, u);
}
__device__ inline unsigned short f2b(float f) {
  unsigned int u = __builtin_bit_cast(unsigned int, f);
  u += 0x7fffu + ((u >> 16) & 1u);   // RNE
  return (unsigned short)(u >> 16);
}

__device__ inline float fast_sigmoid(float x) {
  float t = __builtin_amdgcn_exp2f(-1.4426950408889634f * x);
  return __builtin_amdgcn_rcpf(1.0f + t);
}
__device__ inline float fast_tanh(float x) {
  float t = __builtin_amdgcn_exp2f(2.8853900817779268f * x);
  return 1.0f - 2.0f * __builtin_amdgcn_rcpf(1.0f + t);
}

__device__ inline void gload_lds16(const unsigned short* g, unsigned short* l) {
  __builtin_amdgcn_global_load_lds(
      (const __attribute__((address_space(1))) unsigned int*)(g),
      (__attribute__((address_space(3))) unsigned int*)(l), 16, 0, 0);
}

// compiler memory fence (zero instructions): s_barrier is IntrNoMem to LLVM,
// so memory ops/intrinsics CAN cross it unless pinned. Bracket every barrier.
__device__ inline void cfence() { asm volatile("" ::: "memory"); }
__device__ inline void hard_barrier() {
  cfence();
  __builtin_amdgcn_s_barrier();
  cfence();
}

// ---------------- merged aux kernels (f32 -> bf16 packing) -------------------

__global__ void aux_inputs(const float* __restrict__ word,
                           const float* __restrict__ tag,
                           const float* __restrict__ rel,
                           const float* __restrict__ hprev,
                           const float* __restrict__ kin,
                           unsigned short* __restrict__ xcat,
                           unsigned short* __restrict__ hprevb,
                           unsigned short* __restrict__ kb) {
  int b = blockIdx.x;
  if (b < 26624) {                       // pack_x: N*KPAD elements
    int idx = b * 256 + threadIdx.x;
    if (idx >= NROWS * KPAD) return;
    int n = idx / KPAD, c = idx % KPAD;
    float v = 0.f;
    if (c < 300)      v = word[n * 300 + c];
    else if (c < 350) v = tag[n * 50 + (c - 300)];
    else if (c < 400) v = rel[n * 50 + (c - 350)];
    xcat[idx] = f2b(v);
  } else {                               // cvt hprev / k (8192 blocks each)
    int b2 = b - 26624;
    const float* in = (b2 < 8192) ? hprev : kin;
    unsigned short* out = (b2 < 8192) ? hprevb : kb;
    int i = (((b2 & 8191) * 256) + threadIdx.x) * 4;
    float4 v = *(const float4*)(in + i);
    ushort4 o;
    o.x = f2b(v.x); o.y = f2b(v.y); o.z = f2b(v.z); o.w = f2b(v.w);
    *(ushort4*)(out + i) = o;
  }
}

__global__ void aux_weights(const float* __restrict__ Ww, const float* __restrict__ Wt,
                            const float* __restrict__ Wr,
                            const float* __restrict__ Wh, const float* __restrict__ Wl,
                            const float* __restrict__ Whp, const float* __restrict__ Wk,
                            const float* __restrict__ bw, const float* __restrict__ bt,
                            const float* __restrict__ br, const float* __restrict__ bh,
                            const float* __restrict__ bl, const float* __restrict__ bhp,
                            const float* __restrict__ bk,
                            unsigned short* __restrict__ Wcat,
                            unsigned short* __restrict__ Whb, unsigned short* __restrict__ Wlb,
                            unsigned short* __restrict__ Whpb, unsigned short* __restrict__ Wkb,
                            float* bias0, float* bias1, float* bias2, float* biasD) {
  int b = blockIdx.x;
  if (b < 4160) {                        // pack_w: 2560*KPAD
    int idx = b * 256 + threadIdx.x;
    if (idx >= GATES * HDIM * KPAD) return;
    int gh = idx / KPAD, c = idx % KPAD;
    float v = 0.f;
    if (c < 300)      v = Ww[gh * 300 + c];
    else if (c < 350) v = Wt[gh * 50 + (c - 300)];
    else if (c < 400) v = Wr[gh * 50 + (c - 350)];
    Wcat[idx] = f2b(v);
  } else if (b < 9280) {                 // cvt 4 weight stacks (1280 blocks each)
    int b2 = b - 4160;
    int sel = b2 / 1280;
    const float* in; unsigned short* out;
    switch (sel) {
      case 0: in = Wh;  out = Whb;  break;
      case 1: in = Wl;  out = Wlb;  break;
      case 2: in = Whp; out = Whpb; break;
      default: in = Wk; out = Wkb;  break;
    }
    int i = (((b2 % 1280) * 256) + threadIdx.x) * 4;
    float4 v = *(const float4*)(in + i);
    ushort4 o;
    o.x = f2b(v.x); o.y = f2b(v.y); o.z = f2b(v.z); o.w = f2b(v.w);
    *(ushort4*)(out + i) = o;
  } else {                               // pack_bias (10 blocks)
    int i = (b - 9280) * 256 + threadIdx.x;
    if (i < GATES * HDIM) {
      bias0[i] = bw[i] + bt[i] + br[i];
      bias1[i] = bh[i];
      bias2[i] = bl[i];
      biasD[i] = bhp[i] + bk[i];
    }
  }
}

// ---------------- shared GEMM machinery ------------------------------------
// 256x128 tile, BK=32, 8 waves, 3-buf ring, XCD grid 1280 = 8 x 160
// col-fastest, zero-conflict swizzle q^((r>>1)&3), coalesced epilogue.
// Round 18: SINGLE barrier per K-tile. Safety: reads of buf[(s-1)%3] finish
// before any wave reaches BARRIER(s) (consumed by MFMA pre-barrier); the
// stage of buf[(s+2)%3] (= same buffer) is issued strictly post-BARRIER(s).
// Each wave drains its own tile-s loads (vmcnt(3)) pre-barrier, so post-
// barrier all waves' staged data is landed. End-of-loop hard_barrier guards
// the next writer (runloop2 prologue / epilogue eps aliasing).

// ---------------- stages 1-2: Out = tanh(A*W^T + bias) ----------------------

__global__ __launch_bounds__(512, 2) void gemm_mlp(
    const unsigned short* __restrict__ A1,
    const unsigned short* __restrict__ W1,
    const float* __restrict__ bias,
    unsigned short* __restrict__ Out,
    int aPerGate, int S, int ld)
{
  __shared__ __align__(16) unsigned short smem[36864];   // 72 KB, aliased
  unsigned short* Ab0 = smem;            // staging A [3][8192]
  unsigned short* Bb0 = smem + 24576;    // staging B [3][4096]
  unsigned short* eps = smem;            // epilogue [64][132]

  const int bid = (int)blockIdx.x;
  const int swz = (bid & 7) * 160 + (bid >> 3);
  const int col = swz % 20, rowt = swz / 20;
  const int row0  = rowt * 256;
  const int gcol0 = col * 128;                 // [0,2560)
  const int g = gcol0 >> 9;
  const size_t aslab = aPerGate ? (size_t)g * NROWS * ld : 0;

  const int t = threadIdx.x;
  const int wid = t >> 6, l = t & 63;
  const int wrow = (wid >> 2) * 128;
  const int wcol = (wid & 3) * 32;
  const int fr = l & 15, q = l >> 4;

  f32x4 acc[8][2];
#pragma unroll
  for (int mi = 0; mi < 8; ++mi)
#pragma unroll
    for (int ni = 0; ni < 2; ++ni)
      acc[mi][ni] = (f32x4){0.f, 0.f, 0.f, 0.f};

  auto stage = [&](int c, int buf) {
    const int kloc = c * 32;
    const int rb = t >> 2;
#pragma unroll
    for (int j = 0; j < 2; ++j) {
      const int r = j * 128 + rb;
      const int sgj = ((t & 3) ^ ((r >> 1) & 3)) * 8;
      gload_lds16(A1 + aslab + (size_t)(row0 + r) * ld + kloc + sgj, &Ab0[buf * 8192 + j * 4096 + t * 8]);
    }
    const int sg = ((t & 3) ^ ((rb >> 1) & 3)) * 8;
    gload_lds16(W1 + (size_t)(gcol0 + rb) * ld + kloc + sg, &Bb0[buf * 4096 + t * 8]);
  };

  cfence();
  stage(0, 0);
  if (S > 1) stage(1, 1);
  cfence();

  for (int s = 0; s < S; ++s) {
    const int buf = s % 3;
    if (s < S - 1) asm volatile("s_waitcnt vmcnt(3)" ::: "memory");  // tile s landed
    else           asm volatile("s_waitcnt vmcnt(0)" ::: "memory");
    hard_barrier();
    if (s + 2 < S) stage(s + 2, (s + 2) % 3);   // post-barrier: buf reads done

    bf16x8 bq[2];
#pragma unroll
    for (int ni = 0; ni < 2; ++ni) {
      const int r = wcol + ni * 16 + fr;
      bq[ni] = *reinterpret_cast<const bf16x8*>(&Bb0[buf * 4096 + r * 32 + ((q ^ ((r >> 1) & 3)) * 8)]);
    }
#pragma unroll
    for (int p = 0; p < 2; ++p) {
      bf16x8 af[4];
#pragma unroll
      for (int mi = 0; mi < 4; ++mi) {
        const int r = wrow + (p * 4 + mi) * 16 + fr;
        af[mi] = *reinterpret_cast<const bf16x8*>(&Ab0[buf * 8192 + r * 32 + ((q ^ ((r >> 1) & 3)) * 8)]);
      }
      __builtin_amdgcn_s_setprio(1);
#pragma unroll
      for (int mi = 0; mi < 4; ++mi)
#pragma unroll
        for (int ni = 0; ni < 2; ++ni)
          acc[p * 4 + mi][ni] = __builtin_amdgcn_mfma_f32_16x16x32_bf16(af[mi], bq[ni], acc[p * 4 + mi][ni], 0, 0, 0);
      __builtin_amdgcn_s_setprio(0);
    }
  }
  hard_barrier();   // all K-loop LDS reads done before eps aliasing writes

  // coalesced epilogue
  const size_t NM = (size_t)NROWS * HDIM;
  unsigned short* outg = Out + (size_t)g * NM;
  const int colbase = gcol0 & 511;
  float bv[2];
#pragma unroll
  for (int ni = 0; ni < 2; ++ni)
    bv[ni] = bias[g * HDIM + colbase + wcol + ni * 16 + fr];

#pragma unroll
  for (int h = 0; h < 4; ++h) {
    hard_barrier();                        // prior read-pass done
    if ((wid >> 2) == (h >> 1)) {
      const int mib = (h & 1) * 4;
#pragma unroll
      for (int mi2 = 0; mi2 < 4; ++mi2)
#pragma unroll
        for (int ni = 0; ni < 2; ++ni)
#pragma unroll
          for (int j = 0; j < 4; ++j)
            eps[(mi2 * 16 + q * 4 + j) * 132 + wcol + ni * 16 + fr] =
                f2b(fast_tanh(acc[mib + mi2][ni][j] + bv[ni]));
    }
    asm volatile("s_waitcnt lgkmcnt(0)" ::: "memory");   // publish eps writes
    hard_barrier();
#pragma unroll
    for (int v = 0; v < 2; ++v) {
      const int c  = v * 512 + t;
      const int rl = c >> 4;
      const int cc = (c & 15) * 8;
      const int gr = row0 + h * 64 + rl;
      bf16x8 pv = *reinterpret_cast<const bf16x8*>(&eps[rl * 132 + cc]);
      *reinterpret_cast<bf16x8*>(&outg[(size_t)gr * HDIM + colbase + cc]) = pv;
    }
  }
}

// ---------------- fused stages C+D: gates = act(tanh(h1 Wl^T + b2) + bD
//                                               + hprev Whp^T + k Wk^T) -------

__global__ __launch_bounds__(512, 2) void gemm_cd(
    const unsigned short* __restrict__ H1,    // [G][N][512]
    const unsigned short* __restrict__ Hp,    // [N][512]
    const unsigned short* __restrict__ Kb,    // [N][512]
    const unsigned short* __restrict__ Wl,    // [2560][512]
    const unsigned short* __restrict__ Whp,   // [2560][512]
    const unsigned short* __restrict__ Wk,    // [2560][512]
    const float* __restrict__ bias2, const float* __restrict__ biasD,
    unsigned short* __restrict__ Out)         // gates [G][N][512]
{
  __shared__ __align__(16) unsigned short smem[36864];
  unsigned short* Ab0 = smem;
  unsigned short* Bb0 = smem + 24576;
  unsigned short* eps = smem;

  const int bid = (int)blockIdx.x;
  const int swz = (bid & 7) * 160 + (bid >> 3);
  const int col = swz % 20, rowt = swz / 20;
  const int row0  = rowt * 256;
  const int gcol0 = col * 128;
  const int g = gcol0 >> 9;

  const int t = threadIdx.x;
  const int wid = t >> 6, l = t & 63;
  const int wrow = (wid >> 2) * 128;
  const int wcol = (wid & 3) * 32;
  const int fr = l & 15, q = l >> 4;

  f32x4 acc[8][2];
#pragma unroll
  for (int mi = 0; mi < 8; ++mi)
#pragma unroll
    for (int ni = 0; ni < 2; ++ni)
      acc[mi][ni] = (f32x4){0.f, 0.f, 0.f, 0.f};

  auto stageG = [&](const unsigned short* Asrc, const unsigned short* Wsrc,
                    int kloc, int buf) {
    const int rb = t >> 2;
#pragma unroll
    for (int j = 0; j < 2; ++j) {
      const int r = j * 128 + rb;
      const int sgj = ((t & 3) ^ ((r >> 1) & 3)) * 8;
      gload_lds16(Asrc + (size_t)(row0 + r) * HDIM + kloc + sgj, &Ab0[buf * 8192 + j * 4096 + t * 8]);
    }
    const int sg = ((t & 3) ^ ((rb >> 1) & 3)) * 8;
    gload_lds16(Wsrc + (size_t)(gcol0 + rb) * HDIM + kloc + sg, &Bb0[buf * 4096 + t * 8]);
  };

  auto runloop = [&](int S, auto srcpick) {
    cfence();
    { auto s0 = srcpick(0); stageG(s0.a, s0.w, s0.k, 0); }
    if (S > 1) { auto s1 = srcpick(1); stageG(s1.a, s1.w, s1.k, 1); }
    cfence();
    for (int s = 0; s < S; ++s) {
      const int buf = s % 3;
      if (s < S - 1) asm volatile("s_waitcnt vmcnt(3)" ::: "memory");
      else           asm volatile("s_waitcnt vmcnt(0)" ::: "memory");
      hard_barrier();
      if (s + 2 < S) {
        auto sn = srcpick(s + 2);
        stageG(sn.a, sn.w, sn.k, (s + 2) % 3);
      }

      bf16x8 bq[2];
#pragma unroll
      for (int ni = 0; ni < 2; ++ni) {
        const int r = wcol + ni * 16 + fr;
        bq[ni] = *reinterpret_cast<const bf16x8*>(&Bb0[buf * 4096 + r * 32 + ((q ^ ((r >> 1) & 3)) * 8)]);
      }
#pragma unroll
      for (int p = 0; p < 2; ++p) {
        bf16x8 af[4];
#pragma unroll
        for (int mi = 0; mi < 4; ++mi) {
          const int r = wrow + (p * 4 + mi) * 16 + fr;
          af[mi] = *reinterpret_cast<const bf16x8*>(&Ab0[buf * 8192 + r * 32 + ((q ^ ((r >> 1) & 3)) * 8)]);
        }
        __builtin_amdgcn_s_setprio(1);
#pragma unroll
        for (int mi = 0; mi < 4; ++mi)
#pragma unroll
          for (int ni = 0; ni < 2; ++ni)
            acc[p * 4 + mi][ni] = __builtin_amdgcn_mfma_f32_16x16x32_bf16(af[mi], bq[ni], acc[p * 4 + mi][ni], 0, 0, 0);
        __builtin_amdgcn_s_setprio(0);
      }
    }
    hard_barrier();   // all reads done before next writer touches the ring
  };

  struct Src { const unsigned short* a; const unsigned short* w; int k; };
  const size_t NM = (size_t)NROWS * HDIM;

  // GEMM1: acc = h1[g] * Wl[g]^T   (K=512)
  const unsigned short* h1g = H1 + (size_t)g * NM;
  runloop(16, [&](int c) -> Src { return {h1g, Wl, c * 32}; });

  // in-place accumulator transform: acc = tanh(acc + bias2) + biasD
  const int colbase = gcol0 & 511;
#pragma unroll
  for (int ni = 0; ni < 2; ++ni) {
    const float b2 = bias2[g * HDIM + colbase + wcol + ni * 16 + fr];
    const float bD = biasD[g * HDIM + colbase + wcol + ni * 16 + fr];
#pragma unroll
    for (int mi = 0; mi < 8; ++mi)
#pragma unroll
      for (int j = 0; j < 4; ++j)
        acc[mi][ni][j] = fast_tanh(acc[mi][ni][j] + b2) + bD;
  }

  // GEMM2: acc += hprev * Whp[g]^T + k * Wk[g]^T   (K=1024)
  runloop(32, [&](int c) -> Src {
    return (c < 16) ? Src{Hp, Whp, c * 32} : Src{Kb, Wk, (c - 16) * 32};
  });

  // epilogue: gate activation at LDS-write, coalesced copy out
  unsigned short* outg = Out + (size_t)g * NM;
#pragma unroll
  for (int h = 0; h < 4; ++h) {
    hard_barrier();
    if ((wid >> 2) == (h >> 1)) {
      const int mib = (h & 1) * 4;
#pragma unroll
      for (int mi2 = 0; mi2 < 4; ++mi2)
#pragma unroll
        for (int ni = 0; ni < 2; ++ni)
#pragma unroll
          for (int j = 0; j < 4; ++j) {
            float v = acc[mib + mi2][ni][j];
            v = (g < 4) ? fast_sigmoid(v) : fast_tanh(v);
            eps[(mi2 * 16 + q * 4 + j) * 132 + wcol + ni * 16 + fr] = f2b(v);
          }
    }
    asm volatile("s_waitcnt lgkmcnt(0)" ::: "memory");   // publish eps writes
    hard_barrier();
#pragma unroll
    for (int v = 0; v < 2; ++v) {
      const int c  = v * 512 + t;
      const int rl = c >> 4;
      const int cc = (c & 15) * 8;
      const int gr = row0 + h * 64 + rl;
      bf16x8 pv = *reinterpret_cast<const bf16x8*>(&eps[rl * 132 + cc]);
      *reinterpret_cast<bf16x8*>(&outg[(size_t)gr * HDIM + colbase + cc]) = pv;
    }
  }
}

// ---------------- final elementwise combine (f32 q/c_prev, f32 out) ---------

__device__ inline float exb(const uint4& v, int j) {
  unsigned int wd = ((const unsigned int*)&v)[j >> 1];
  return b2f((unsigned short)(wd >> ((j & 1) * 16)));
}

__global__ void combine(const unsigned short* __restrict__ gates,
                        const float* __restrict__ q,
                        const float* __restrict__ cp,
                        float* __restrict__ out) {
  const size_t NM = (size_t)NROWS * HDIM;
  size_t i8 = ((size_t)blockIdx.x * 256 + threadIdx.x) * 8;
  if (i8 >= NM) return;
  uint4 gi = *(const uint4*)(gates + 0 * NM + i8);
  uint4 gf = *(const uint4*)(gates + 1 * NM + i8);
  uint4 gl = *(const uint4*)(gates + 2 * NM + i8);
  uint4 go = *(const uint4*)(gates + 3 * NM + i8);
  uint4 gu = *(const uint4*)(gates + 4 * NM + i8);
  float4 q0 = *(const float4*)(q + i8);
  float4 q1 = *(const float4*)(q + i8 + 4);
  float4 p0 = *(const float4*)(cp + i8);
  float4 p1 = *(const float4*)(cp + i8 + 4);
  float qv[8] = {q0.x, q0.y, q0.z, q0.w, q1.x, q1.y, q1.z, q1.w};
  float pv[8] = {p0.x, p0.y, p0.z, p0.w, p1.x, p1.y, p1.z, p1.w};
  float hv[8], cv[8];
#pragma unroll
  for (int j = 0; j < 8; ++j) {
    float c = exb(gi, j) * exb(gu, j) + exb(gf, j) * qv[j] + exb(gl, j) * pv[j];
    hv[j] = exb(go, j) * fast_tanh(c);
    cv[j] = c;
  }
  *(float4*)(out + i8)      = make_float4(hv[0], hv[1], hv[2], hv[3]);
  *(float4*)(out + i8 + 4)  = make_float4(hv[4], hv[5], hv[6], hv[7]);
  *(float4*)(out + NM + i8)     = make_float4(cv[0], cv[1], cv[2], cv[3]);
  *(float4*)(out + NM + i8 + 4) = make_float4(cv[4], cv[5], cv[6], cv[7]);
}

// ---------------- launch ----------------

extern "C" void kernel_launch(void* const* d_in, const int* in_sizes, int n_in,
                              void* d_out, int out_size, void* d_ws, size_t ws_size,
                              hipStream_t stream) {
  const float* word  = (const float*)d_in[0];
  const float* tag   = (const float*)d_in[1];
  const float* rel   = (const float*)d_in[2];
  const float* kin   = (const float*)d_in[3];
  const float* qin   = (const float*)d_in[4];
  const float* hprev = (const float*)d_in[5];
  const float* cprev = (const float*)d_in[6];
  const float* Ww    = (const float*)d_in[7];
  const float* bw    = (const float*)d_in[8];
  const float* Wt    = (const float*)d_in[9];
  const float* bt    = (const float*)d_in[10];
  const float* Wr    = (const float*)d_in[11];
  const float* br    = (const float*)d_in[12];
  const float* Wh    = (const float*)d_in[13];
  const float* bh    = (const float*)d_in[14];
  const float* Wl    = (const float*)d_in[15];
  const float* bl    = (const float*)d_in[16];
  const float* Whp   = (const float*)d_in[17];
  const float* bhp   = (const float*)d_in[18];
  const float* Wk    = (const float*)d_in[19];
  const float* bk    = (const float*)d_in[20];

  char* ws = (char*)d_ws;
  unsigned short* xcat   = (unsigned short*)(ws);                 // 13,631,488 B
  unsigned short* Wcat   = (unsigned short*)(ws + 13631488);      //  2,129,920 B
  unsigned short* Whb    = (unsigned short*)(ws + 15761408);      //  2,621,440 B
  unsigned short* Wlb    = (unsigned short*)(ws + 18382848);
  unsigned short* Whpb   = (unsigned short*)(ws + 21004288);
  unsigned short* Wkb    = (unsigned short*)(ws + 23625728);
  unsigned short* hprevb = (unsigned short*)(ws + 26247168);      // 16,777,216 B
  unsigned short* kb16   = (unsigned short*)(ws + 43024384);      // 16,777,216 B
  float* bias0           = (float*)(ws + 59801600);
  float* bias1           = (float*)(ws + 59811840);
  float* bias2           = (float*)(ws + 59822080);
  float* biasD           = (float*)(ws + 59832320);
  unsigned short* bufA   = (unsigned short*)(ws + 59842560);      // 83,886,080 B
  unsigned short* bufB   = (unsigned short*)(ws + 143728640);     // 83,886,080 B
  // total: 227,614,720 B

  aux_inputs<<<43008, 256, 0, stream>>>(word, tag, rel, hprev, kin,
                                        xcat, hprevb, kb16);
  aux_weights<<<9290, 256, 0, stream>>>(Ww, Wt, Wr, Wh, Wl, Whp, Wk,
                                        bw, bt, br, bh, bl, bhp, bk,
                                        Wcat, Whb, Wlb, Whpb, Wkb,
                                        bias0, bias1, bias2, biasD);

  const int grid = (NROWS / 256) * ((GATES * HDIM) / 128);   // 64*20 = 1280
  // h0 = tanh(xcat W0^T + b0)            K=416 (13 tiles)
  gemm_mlp<<<grid, 512, 0, stream>>>(xcat, Wcat, bias0, bufA, 0, 13, KPAD);
  // h1 = tanh(h0 Whid^T + bhid)          K=512
  gemm_mlp<<<grid, 512, 0, stream>>>(bufA, Whb, bias1, bufB, 1, 16, HDIM);
  // gates = act(tanh(h1 Wl^T + b2) + bD + hprev Whp^T + k Wk^T)   fused C+D
  gemm_cd<<<grid, 512, 0, stream>>>(bufB, hprevb, kb16, Wlb, Whpb, Wkb,
                                    bias2, biasD, bufA);
  // c = i*u + f_down*q + f_left*c_prev ; h = o*tanh(c)
  combine<<<4096, 256, 0, stream>>>(bufA, qin, cprev, (float*)d_out);
}